// Round 12
// baseline (16184.663 us; speedup 1.0000x reference)
//
#include <hip/hip_runtime.h>
#include <hip/hip_bf16.h>

#define Bsz 4096
#define Dsz 256
#define Hsz 512
#define Tsz 45

typedef __attribute__((ext_vector_type(8))) short short8;
typedef __attribute__((ext_vector_type(4))) float f32x4;
typedef __attribute__((ext_vector_type(4))) unsigned short us4;
using bf16 = __hip_bfloat16;
using u8 = unsigned char;

__device__ __forceinline__ float sigf(float x)   { return 1.0f / (1.0f + __expf(-x)); }
__device__ __forceinline__ float tanhft(float x) { return 1.0f - 2.0f / (__expf(2.0f * x) + 1.0f); }
__device__ __forceinline__ float b2f(unsigned short u) { return __uint_as_float((unsigned)u << 16); }
__device__ __forceinline__ u8 f2fp8(float v) {
    int p = __builtin_amdgcn_cvt_pk_fp8_f32(v, v, 0, false);
    return (u8)(p & 0xff);
}

// ---------------------------------------------------------------------------
// Weight convert/pack (one-shot). Recurrent weights fp8 in (kt, wave, q)
// blocked fragment-linear 512 B blocks: block id = (kt*8 + wv)*16 + q,
// q = g*4 + jc. Inside a block, byte (n&15, k&31) sits at lq*128+ln*8+(k&7),
// lq=(k>>3)&3 -> a wave's frag is 8 B/lane fully coalesced, and per kt the
// wave's 16 frags are 16 consecutive blocks (one base + imm offsets).
// ---------------------------------------------------------------------------
__global__ void k_conv(const float* __restrict__ ef,   const float* __restrict__ ctx,
                       const float* __restrict__ Whi,  const float* __restrict__ Wci,
                       const float* __restrict__ Wih0, const float* __restrict__ Whh0,
                       const float* __restrict__ Wih1, const float* __restrict__ Whh1,
                       const float* __restrict__ Wo1,  const float* __restrict__ Wg1,
                       bf16* __restrict__ efb,  bf16* __restrict__ ctxb,
                       bf16* __restrict__ Wit,  u8* __restrict__ W0p,
                       u8* __restrict__ W1p,  u8* __restrict__ Wo1p,
                       u8* __restrict__ Wg1p)
{
    size_t tid = (size_t)blockIdx.x * blockDim.x + threadIdx.x;
    size_t gsz = (size_t)gridDim.x * blockDim.x;
    for (size_t i = tid; i < (size_t)Bsz * Dsz; i += gsz) {
        efb[i]  = __float2bfloat16(ef[i]);
        ctxb[i] = __float2bfloat16(ctx[i]);
    }
    for (size_t i = tid; i < 2048ull * 512 / 4; i += gsz) {   // W0p <- Whh0^T
        int n = i >> 7, k = (i & 127) * 4;
        int lo = __builtin_amdgcn_cvt_pk_fp8_f32(Whh0[(size_t)(k+0)*2048+n], Whh0[(size_t)(k+1)*2048+n], 0, false);
        int pk = __builtin_amdgcn_cvt_pk_fp8_f32(Whh0[(size_t)(k+2)*2048+n], Whh0[(size_t)(k+3)*2048+n], lo, true);
        int nb = n >> 4;
        size_t blk = (size_t)((k >> 5) * 8 + ((nb >> 2) & 7)) * 16 + ((nb >> 5) * 4 + (nb & 3));
        *(int*)(W0p + blk * 512 + ((k >> 3) & 3) * 128 + (n & 15) * 8 + (k & 4)) = pk;
    }
    for (size_t i = tid; i < 2048ull * 1024 / 4; i += gsz) {  // W1p <- [Wih1;Whh1]^T
        int n = i >> 8, k = (i & 255) * 4;
        float f0, f1, f2, f3;
        if (k < 512) {
            f0 = Wih1[(size_t)(k+0)*2048+n]; f1 = Wih1[(size_t)(k+1)*2048+n];
            f2 = Wih1[(size_t)(k+2)*2048+n]; f3 = Wih1[(size_t)(k+3)*2048+n];
        } else {
            int kk = k - 512;
            f0 = Whh1[(size_t)(kk+0)*2048+n]; f1 = Whh1[(size_t)(kk+1)*2048+n];
            f2 = Whh1[(size_t)(kk+2)*2048+n]; f3 = Whh1[(size_t)(kk+3)*2048+n];
        }
        int lo = __builtin_amdgcn_cvt_pk_fp8_f32(f0, f1, 0, false);
        int pk = __builtin_amdgcn_cvt_pk_fp8_f32(f2, f3, lo, true);
        int nb = n >> 4;
        size_t blk = (size_t)((k >> 5) * 8 + ((nb >> 2) & 7)) * 16 + ((nb >> 5) * 4 + (nb & 3));
        *(int*)(W1p + blk * 512 + ((k >> 3) & 3) * 128 + (n & 15) * 8 + (k & 4)) = pk;
    }
    for (size_t i = tid; i < 32ull * 512 / 4; i += gsz) {     // Wo1p/Wg1p (N=32, nb*16+kt)
        int n = i >> 7, k = (i & 127) * 4;
        size_t dst = ((size_t)(n >> 4) * 16 + (k >> 5)) * 512 + ((k >> 3) & 3) * 128 + (n & 15) * 8 + (k & 4);
        int lo = __builtin_amdgcn_cvt_pk_fp8_f32(Wo1[(size_t)(k+0)*32+n], Wo1[(size_t)(k+1)*32+n], 0, false);
        int pk = __builtin_amdgcn_cvt_pk_fp8_f32(Wo1[(size_t)(k+2)*32+n], Wo1[(size_t)(k+3)*32+n], lo, true);
        *(int*)(Wo1p + dst) = pk;
        lo = __builtin_amdgcn_cvt_pk_fp8_f32(Wg1[(size_t)(k+0)*32+n], Wg1[(size_t)(k+1)*32+n], 0, false);
        pk = __builtin_amdgcn_cvt_pk_fp8_f32(Wg1[(size_t)(k+2)*32+n], Wg1[(size_t)(k+3)*32+n], lo, true);
        *(int*)(Wg1p + dst) = pk;
    }
    for (size_t i = tid; i < 4096ull * 256; i += gsz) {       // Wit[n][k] bf16
        size_t n = i >> 8, k = i & 255;
        float v = (n < 1024) ? Whi[k * 1024 + n]
                : (n < 2048) ? Wci[k * 1024 + (n - 1024)]
                             : Wih0[(1 + k) * 2048 + (n - 2048)];
        Wit[i] = __float2bfloat16(v);
    }
}

// ---------------------------------------------------------------------------
// Init GEMM (bf16): h stored fp8 plain [b][512], c f32, ctxg bf16 [b][j][4g].
// ---------------------------------------------------------------------------
__global__ void __launch_bounds__(256)
k_init(const bf16* __restrict__ efb, const bf16* __restrict__ ctxb,
       const bf16* __restrict__ Wit,
       const float* __restrict__ bh,  const float* __restrict__ bc,
       const float* __restrict__ bi0, const float* __restrict__ bh0,
       u8* __restrict__ h0, u8* __restrict__ h1,
       float* __restrict__ c0, float* __restrict__ c1,
       bf16* __restrict__ ctxg)
{
    const int t = threadIdx.x, lane = t & 63, w = t >> 6;
    const int wr = w >> 1, wc = w & 1;
    const int lq = lane >> 4, ln = lane & 15;
    const int m0 = blockIdx.x * 128, n0 = blockIdx.y * 64;
    const bf16* A = (n0 < 2048) ? efb : ctxb;

    f32x4 zero = {0.f, 0.f, 0.f, 0.f};
    f32x4 acc[4][2];
#pragma unroll
    for (int r = 0; r < 4; ++r)
#pragma unroll
        for (int c = 0; c < 2; ++c) acc[r][c] = zero;

    for (int k0 = 0; k0 < 256; k0 += 32) {
        short8 af[4];
#pragma unroll
        for (int r = 0; r < 4; ++r)
            af[r] = *(const short8*)(A + (size_t)(m0 + wr * 64 + r * 16 + ln) * 256 + k0 + lq * 8);
#pragma unroll
        for (int c = 0; c < 2; ++c) {
            short8 bv = *(const short8*)(Wit + (size_t)(n0 + wc * 32 + c * 16 + ln) * 256 + k0 + lq * 8);
#pragma unroll
            for (int r = 0; r < 4; ++r)
                acc[r][c] = __builtin_amdgcn_mfma_f32_16x16x32_bf16(af[r], bv, acc[r][c], 0, 0, 0);
        }
    }
#pragma unroll
    for (int r = 0; r < 4; ++r)
#pragma unroll
        for (int c = 0; c < 2; ++c)
#pragma unroll
            for (int e = 0; e < 4; ++e) {
                int b = m0 + wr * 64 + r * 16 + lq * 4 + e;
                int n = n0 + wc * 32 + c * 16 + ln;
                float v = acc[r][c][e];
                if (n < 1024) {
                    v += bh[n];
                    if (n < 512) h0[(size_t)b * 512 + n]       = f2fp8(v);
                    else         h1[(size_t)b * 512 + n - 512] = f2fp8(v);
                } else if (n < 2048) {
                    int m = n - 1024; v += bc[m];
                    if (m < 512) c0[(size_t)b * 512 + m]       = v;
                    else         c1[(size_t)b * 512 + m - 512] = v;
                } else {
                    int j = n - 2048;
                    ctxg[(size_t)b * 2048 + (j & 511) * 4 + (j >> 9)] =
                        __float2bfloat16(v + bi0[j] + bh0[j]);
                }
            }
}

// h-LDS B-frag read (B[k][b=ln]): row=ln, chunk c=4kt+lq, swizzle c^ln (4-bit)
__device__ __forceinline__ long hread(const u8* buf, int ln, int lq, int kt) {
    int c = (kt << 2) + lq;
    return *(const long*)(buf + ln * 512 + ((c ^ ln) << 3));
}

// ---------------------------------------------------------------------------
// Persistent T-loop kernel, operand-swapped (G = W·h^T), with explicit
// double-buffered register prefetch of the weight stream (1 kt ahead) and
// (kt,wave,q)-blocked weight layout (per-kt advance = +64 KB on one base).
// 256 WGs x 512 thr, 8 waves/CU, launch_bounds(512,2) -> 256 VGPR budget.
// ---------------------------------------------------------------------------
__global__ void __launch_bounds__(512, 2)
k_loop(const u8* __restrict__ h0i, const u8* __restrict__ h1i,
       const u8* __restrict__ W0p, const u8* __restrict__ W1p,
       const u8* __restrict__ Wo1p, const u8* __restrict__ Wg1p,
       const bf16* __restrict__ ctxg, const float* __restrict__ ii,
       const float* __restrict__ w0row,
       const float* __restrict__ bi1, const float* __restrict__ bh1,
       const float* __restrict__ bo1, const float* __restrict__ Wo2,
       const float* __restrict__ bo2,
       const float* __restrict__ bg1, const float* __restrict__ Wg2,
       const float* __restrict__ bg2,
       const float* __restrict__ c0g, const float* __restrict__ c1g,
       float* __restrict__ out)
{
    __shared__ u8 h0L[2][16 * 512];
    __shared__ u8 h1L[2][16 * 512];
    __shared__ float a0L[2048];          // w0row (intent rank-1 coeffs)
    __shared__ float a1L[2048];          // bi1 + bh1
    __shared__ float sit[16];
    __shared__ float spart[16][2];

    const int t = threadIdx.x, lane = t & 63, w = t >> 6;
    const int ln = lane & 15, lq = lane >> 4;
    const int m0 = blockIdx.x * 16;
    const int b = m0 + ln;               // this thread's batch row
    f32x4 zero = {0.f, 0.f, 0.f, 0.f};

    // per-wave weight stream bases (q-blocks contiguous; kt step = +65536)
    const u8* bw0 = W0p + (size_t)w * 8192 + lane * 8;
    const u8* bw1 = W1p + (size_t)w * 8192 + lane * 8;

    // ---- prologue: h-init -> LDS (swizzled chunk^row)
#pragma unroll
    for (int i = 0; i < 2; ++i) {
        int cid = i * 512 + t;
        int row = cid >> 6, c = cid & 63;
        long v0 = *(const long*)(h0i + (size_t)(m0 + row) * 512 + c * 8);
        long v1 = *(const long*)(h1i + (size_t)(m0 + row) * 512 + c * 8);
        int pc = row * 512 + ((c ^ row) << 3);
        *(long*)(&h0L[0][pc]) = v0;
        *(long*)(&h1L[0][pc]) = v1;
    }
#pragma unroll
    for (int i = 0; i < 4; ++i) {
        int idx = i * 512 + t;
        a0L[idx] = w0row[idx];
        a1L[idx] = bi1[idx] + bh1[idx];
    }
    // ---- per-thread state: c and ctxg at (b=ln, jl=(w*4+jc)*16+lq*4+e)
    f32x4 cr0[4], cr1[4];
    us4 xg[4][4];
#pragma unroll
    for (int jc = 0; jc < 4; ++jc) {
        int jlb = (w * 4 + jc) * 16 + lq * 4;
        cr0[jc] = *(const f32x4*)(c0g + (size_t)b * 512 + jlb);
        cr1[jc] = *(const f32x4*)(c1g + (size_t)b * 512 + jlb);
#pragma unroll
        for (int e = 0; e < 4; ++e)
            xg[jc][e] = *(const us4*)((const unsigned short*)ctxg + (size_t)b * 2048 + (jlb + e) * 4);
    }
    __syncthreads();

    // intent head: waves 0,1 do j-tiles 0,1 (16 cols each); all call (barriers)
    auto head2 = [&](const u8* hbuf, const u8* Wp, const float* b1,
                     const float* W2, float b2s, bool tosit,
                     float* dst, int stride, int scol) {
        if (w < 2) {
            f32x4 acc = zero;
#pragma unroll
            for (int kt = 0; kt < 16; ++kt) {
                long bf = hread(hbuf, ln, lq, kt);
                long af = *(const long*)(Wp + (size_t)(w * 16 + kt) * 512 + lane * 8);
                acc = __builtin_amdgcn_mfma_f32_16x16x32_fp8_fp8(af, bf, acc, 0, 0, 0);
            }
            float v = 0.f;
#pragma unroll
            for (int e = 0; e < 4; ++e) {
                int j = w * 16 + lq * 4 + e;
                v += fmaxf(acc[e] + b1[j], 0.f) * W2[j];
            }
            v += __shfl_xor(v, 16);
            v += __shfl_xor(v, 32);
            if (lq == 0) spart[ln][w] = v;
        }
        __syncthreads();
        if (t < 16) {
            float pv = sigf(spart[t][0] + spart[t][1] + b2s);
            if (tosit) sit[t] = pv;
            if (dst) dst[(size_t)(m0 + t) * stride + scol] = pv;
        }
        __syncthreads();
    };

    for (int s = 0; s < Tsz; ++s) {
        const int p = s & 1;
        const u8* h0c = h0L[p];
        u8*       h0n = h0L[1 - p];
        const u8* h1c = h1L[p];
        u8*       h1n = h1L[1 - p];

        // ---- intent for this step (head of h1_{s-1}); writes out col s-1
        if (s == 0) {
            if (t < 16) sit[t] = ii[m0 + t];
            __syncthreads();
        } else {
            head2(h1c, Wo1p, bo1, Wo2, bo2[0], true, out, Tsz, s - 1);
        }
        const float sval = sit[ln];

        // ---- layer 0: G = W0·h0^T, K=512, double-buffered weight prefetch
        {
            long wfA[16], wfB[16];
            f32x4 acc[4][4];                 // [jc][g]
#pragma unroll
            for (int jc = 0; jc < 4; ++jc)
#pragma unroll
                for (int g = 0; g < 4; ++g) acc[jc][g] = zero;
#pragma unroll
            for (int q = 0; q < 16; ++q)
                wfA[q] = *(const long*)(bw0 + q * 512);            // kt = 0
#pragma unroll
            for (int kt = 0; kt < 16; kt += 2) {
#pragma unroll
                for (int q = 0; q < 16; ++q)                       // kt+1 -> B
                    wfB[q] = *(const long*)(bw0 + (size_t)(kt + 1) * 65536 + q * 512);
                long bf = hread(h0c, ln, lq, kt);
#pragma unroll
                for (int q = 0; q < 16; ++q)
                    acc[q & 3][q >> 2] = __builtin_amdgcn_mfma_f32_16x16x32_fp8_fp8(
                        wfA[q], bf, acc[q & 3][q >> 2], 0, 0, 0);
                if (kt + 2 < 16) {
#pragma unroll
                    for (int q = 0; q < 16; ++q)                   // kt+2 -> A
                        wfA[q] = *(const long*)(bw0 + (size_t)(kt + 2) * 65536 + q * 512);
                }
                long bf2 = hread(h0c, ln, lq, kt + 1);
#pragma unroll
                for (int q = 0; q < 16; ++q)
                    acc[q & 3][q >> 2] = __builtin_amdgcn_mfma_f32_16x16x32_fp8_fp8(
                        wfB[q], bf2, acc[q & 3][q >> 2], 0, 0, 0);
            }
#pragma unroll
            for (int jc = 0; jc < 4; ++jc) {
                int jlb = (w * 4 + jc) * 16 + lq * 4;
                f32x4 a0v[4];
#pragma unroll
                for (int g = 0; g < 4; ++g) a0v[g] = *(const f32x4*)(a0L + g * 512 + jlb);
                float hv[4];
#pragma unroll
                for (int e = 0; e < 4; ++e) {
                    float pre[4];
#pragma unroll
                    for (int g = 0; g < 4; ++g)
                        pre[g] = acc[jc][g][e] + b2f(xg[jc][e][g]) + sval * a0v[g][e];
                    float ig = sigf(pre[0]), fg = sigf(pre[1]);
                    float gg = tanhft(pre[2]), og = sigf(pre[3]);
                    float cn = fg * cr0[jc][e] + ig * gg;
                    cr0[jc][e] = cn;
                    hv[e] = og * tanhft(cn);
                }
                int lo = __builtin_amdgcn_cvt_pk_fp8_f32(hv[0], hv[1], 0, false);
                int u  = __builtin_amdgcn_cvt_pk_fp8_f32(hv[2], hv[3], lo, true);
                int c = (w * 4 + jc) * 2 + (lq >> 1);
                *(int*)(h0n + ln * 512 + ((c ^ ln) << 3) + (lq & 1) * 4) = u;
            }
        }
        __syncthreads();                       // h0n complete

        // ---- layer 1: G = W1·[h0n;h1c]^T, K=1024, same prefetch scheme
        {
            long wfA[16], wfB[16];
            f32x4 acc[4][4];
#pragma unroll
            for (int jc = 0; jc < 4; ++jc)
#pragma unroll
                for (int g = 0; g < 4; ++g) acc[jc][g] = zero;
#pragma unroll
            for (int q = 0; q < 16; ++q)
                wfA[q] = *(const long*)(bw1 + q * 512);            // kt = 0
#pragma unroll
            for (int kt = 0; kt < 32; kt += 2) {
#pragma unroll
                for (int q = 0; q < 16; ++q)
                    wfB[q] = *(const long*)(bw1 + (size_t)(kt + 1) * 65536 + q * 512);
                long bf = (kt < 16) ? hread(h0n, ln, lq, kt) : hread(h1c, ln, lq, kt - 16);
#pragma unroll
                for (int q = 0; q < 16; ++q)
                    acc[q & 3][q >> 2] = __builtin_amdgcn_mfma_f32_16x16x32_fp8_fp8(
                        wfA[q], bf, acc[q & 3][q >> 2], 0, 0, 0);
                if (kt + 2 < 32) {
#pragma unroll
                    for (int q = 0; q < 16; ++q)
                        wfA[q] = *(const long*)(bw1 + (size_t)(kt + 2) * 65536 + q * 512);
                }
                long bf2 = (kt + 1 < 16) ? hread(h0n, ln, lq, kt + 1) : hread(h1c, ln, lq, kt - 15);
#pragma unroll
                for (int q = 0; q < 16; ++q)
                    acc[q & 3][q >> 2] = __builtin_amdgcn_mfma_f32_16x16x32_fp8_fp8(
                        wfB[q], bf2, acc[q & 3][q >> 2], 0, 0, 0);
            }
#pragma unroll
            for (int jc = 0; jc < 4; ++jc) {
                int jlb = (w * 4 + jc) * 16 + lq * 4;
                f32x4 a1v[4];
#pragma unroll
                for (int g = 0; g < 4; ++g) a1v[g] = *(const f32x4*)(a1L + g * 512 + jlb);
                float hv[4];
#pragma unroll
                for (int e = 0; e < 4; ++e) {
                    float pre[4];
#pragma unroll
                    for (int g = 0; g < 4; ++g) pre[g] = acc[jc][g][e] + a1v[g][e];
                    float ig = sigf(pre[0]), fg = sigf(pre[1]);
                    float gg = tanhft(pre[2]), og = sigf(pre[3]);
                    float cn = fg * cr1[jc][e] + ig * gg;
                    cr1[jc][e] = cn;
                    hv[e] = og * tanhft(cn);
                }
                int lo = __builtin_amdgcn_cvt_pk_fp8_f32(hv[0], hv[1], 0, false);
                int u  = __builtin_amdgcn_cvt_pk_fp8_f32(hv[2], hv[3], lo, true);
                int c = (w * 4 + jc) * 2 + (lq >> 1);
                *(int*)(h1n + ln * 512 + ((c ^ ln) << 3) + (lq & 1) * 4) = u;
            }
        }
        __syncthreads();                       // h1n complete (step end)
    }

    // ---- final heads: h1 final = h1L[1] (s=44: p=0 wrote 1-p=1)
    head2(h1L[1], Wo1p, bo1, Wo2, bo2[0], false, out, Tsz, 44);
    head2(h1L[1], Wg1p, bg1, Wg2, bg2[0], false, out + (size_t)Bsz * Tsz, 1, 0);
}

// ---------------------------------------------------------------------------
extern "C" void kernel_launch(void* const* d_in, const int* in_sizes, int n_in,
                              void* d_out, int out_size, void* d_ws, size_t ws_size,
                              hipStream_t stream)
{
    const float* ef   = (const float*)d_in[0];
    const float* ctx  = (const float*)d_in[1];
    const float* ii   = (const float*)d_in[2];
    const float* Whi  = (const float*)d_in[3];
    const float* bh   = (const float*)d_in[4];
    const float* Wci  = (const float*)d_in[5];
    const float* bc   = (const float*)d_in[6];
    const float* Wih0 = (const float*)d_in[7];
    const float* Whh0 = (const float*)d_in[8];
    const float* bi0  = (const float*)d_in[9];
    const float* bh0  = (const float*)d_in[10];
    const float* Wih1 = (const float*)d_in[11];
    const float* Whh1 = (const float*)d_in[12];
    const float* bi1  = (const float*)d_in[13];
    const float* bh1  = (const float*)d_in[14];
    const float* Wo1  = (const float*)d_in[15];
    const float* bo1  = (const float*)d_in[16];
    const float* Wo2  = (const float*)d_in[17];
    const float* bo2  = (const float*)d_in[18];
    const float* Wg1  = (const float*)d_in[19];
    const float* bg1  = (const float*)d_in[20];
    const float* Wg2  = (const float*)d_in[21];
    const float* bg2  = (const float*)d_in[22];
    float* out = (float*)d_out;

    char* ws = (char*)d_ws;
    size_t off = 0;
    auto take = [&](size_t bytes) -> char* {
        char* pp = ws + off;
        off += (bytes + 255) & ~(size_t)255;
        return pp;
    };
    u8*  W0p     = (u8*)take(2048ull * 512);
    u8*  W1p     = (u8*)take(2048ull * 1024);
    u8*  Wo1p    = (u8*)take(32ull * 512);
    u8*  Wg1p    = (u8*)take(32ull * 512);
    bf16* Wit    = (bf16*)take(4096ull * 256 * 2);
    bf16* efb    = (bf16*)take((size_t)Bsz * Dsz * 2);
    bf16* ctxb   = (bf16*)take((size_t)Bsz * Dsz * 2);
    u8*  h0x     = (u8*)take((size_t)Bsz * Hsz);
    u8*  h1x     = (u8*)take((size_t)Bsz * Hsz);
    float* c0    = (float*)take((size_t)Bsz * Hsz * 4);
    float* c1    = (float*)take((size_t)Bsz * Hsz * 4);
    bf16* ctxg   = (bf16*)take((size_t)Bsz * 2048 * 2);
    (void)ws_size; (void)in_sizes; (void)n_in; (void)out_size;

    k_conv<<<2048, 256, 0, stream>>>(ef, ctx, Whi, Wci, Wih0, Whh0, Wih1, Whh1, Wo1, Wg1,
                                     efb, ctxb, Wit, W0p, W1p, Wo1p, Wg1p);
    k_init<<<dim3(32, 64), 256, 0, stream>>>(efb, ctxb, Wit, bh, bc, bi0, bh0,
                                             h0x, h1x, c0, c1, ctxg);
    k_loop<<<256, 512, 0, stream>>>(h0x, h1x, W0p, W1p, Wo1p, Wg1p,
                                    ctxg, ii, Wih0, bi1, bh1,
                                    bo1, Wo2, bo2, bg1, Wg2, bg2,
                                    c0, c1, out);
}

// Round 13
// 2681.174 us; speedup vs baseline: 6.0364x; 6.0364x over previous
//
#include <hip/hip_runtime.h>
#include <hip/hip_bf16.h>

#define Bsz 4096
#define Dsz 256
#define Hsz 512
#define Tsz 45

typedef __attribute__((ext_vector_type(8))) short short8;
typedef __attribute__((ext_vector_type(4))) float f32x4;
typedef __attribute__((ext_vector_type(4))) unsigned short us4;
using bf16 = __hip_bfloat16;
using u8 = unsigned char;

__device__ __forceinline__ float sigf(float x)   { return 1.0f / (1.0f + __expf(-x)); }
__device__ __forceinline__ float tanhft(float x) { return 1.0f - 2.0f / (__expf(2.0f * x) + 1.0f); }
__device__ __forceinline__ float b2f(unsigned short u) { return __uint_as_float((unsigned)u << 16); }
__device__ __forceinline__ u8 f2fp8(float v) {
    int p = __builtin_amdgcn_cvt_pk_fp8_f32(v, v, 0, false);
    return (u8)(p & 0xff);
}

__device__ __forceinline__ void gload16(const void* g, void* l) {
    __builtin_amdgcn_global_load_lds((const __attribute__((address_space(1))) void*)g,
                                     (__attribute__((address_space(3))) void*)l, 16, 0, 0);
}

#define WAIT_VM(N) asm volatile("s_waitcnt vmcnt(" #N ")" ::: "memory")
#define WAIT_LGKM0 asm volatile("s_waitcnt lgkmcnt(0)" ::: "memory")

// ---------------------------------------------------------------------------
// Weight convert/pack (one-shot, identical to R12 — proven numerics).
// fp8 weights in (kt, wave, q) blocked 512 B fragment blocks:
// block id = (kt*8 + wv)*16 + q, q = g*4 + jc; inside a block byte (n&15,k&31)
// at lq*128+ln*8+(k&7). A wave's 16 frags for one kt = 8 KB contiguous.
// ---------------------------------------------------------------------------
__global__ void k_conv(const float* __restrict__ ef,   const float* __restrict__ ctx,
                       const float* __restrict__ Whi,  const float* __restrict__ Wci,
                       const float* __restrict__ Wih0, const float* __restrict__ Whh0,
                       const float* __restrict__ Wih1, const float* __restrict__ Whh1,
                       const float* __restrict__ Wo1,  const float* __restrict__ Wg1,
                       bf16* __restrict__ efb,  bf16* __restrict__ ctxb,
                       bf16* __restrict__ Wit,  u8* __restrict__ W0p,
                       u8* __restrict__ W1p,  u8* __restrict__ Wo1p,
                       u8* __restrict__ Wg1p)
{
    size_t tid = (size_t)blockIdx.x * blockDim.x + threadIdx.x;
    size_t gsz = (size_t)gridDim.x * blockDim.x;
    for (size_t i = tid; i < (size_t)Bsz * Dsz; i += gsz) {
        efb[i]  = __float2bfloat16(ef[i]);
        ctxb[i] = __float2bfloat16(ctx[i]);
    }
    for (size_t i = tid; i < 2048ull * 512 / 4; i += gsz) {   // W0p <- Whh0^T
        int n = i >> 7, k = (i & 127) * 4;
        int lo = __builtin_amdgcn_cvt_pk_fp8_f32(Whh0[(size_t)(k+0)*2048+n], Whh0[(size_t)(k+1)*2048+n], 0, false);
        int pk = __builtin_amdgcn_cvt_pk_fp8_f32(Whh0[(size_t)(k+2)*2048+n], Whh0[(size_t)(k+3)*2048+n], lo, true);
        int nb = n >> 4;
        size_t blk = (size_t)((k >> 5) * 8 + ((nb >> 2) & 7)) * 16 + ((nb >> 5) * 4 + (nb & 3));
        *(int*)(W0p + blk * 512 + ((k >> 3) & 3) * 128 + (n & 15) * 8 + (k & 4)) = pk;
    }
    for (size_t i = tid; i < 2048ull * 1024 / 4; i += gsz) {  // W1p <- [Wih1;Whh1]^T
        int n = i >> 8, k = (i & 255) * 4;
        float f0, f1, f2, f3;
        if (k < 512) {
            f0 = Wih1[(size_t)(k+0)*2048+n]; f1 = Wih1[(size_t)(k+1)*2048+n];
            f2 = Wih1[(size_t)(k+2)*2048+n]; f3 = Wih1[(size_t)(k+3)*2048+n];
        } else {
            int kk = k - 512;
            f0 = Whh1[(size_t)(kk+0)*2048+n]; f1 = Whh1[(size_t)(kk+1)*2048+n];
            f2 = Whh1[(size_t)(kk+2)*2048+n]; f3 = Whh1[(size_t)(kk+3)*2048+n];
        }
        int lo = __builtin_amdgcn_cvt_pk_fp8_f32(f0, f1, 0, false);
        int pk = __builtin_amdgcn_cvt_pk_fp8_f32(f2, f3, lo, true);
        int nb = n >> 4;
        size_t blk = (size_t)((k >> 5) * 8 + ((nb >> 2) & 7)) * 16 + ((nb >> 5) * 4 + (nb & 3));
        *(int*)(W1p + blk * 512 + ((k >> 3) & 3) * 128 + (n & 15) * 8 + (k & 4)) = pk;
    }
    for (size_t i = tid; i < 32ull * 512 / 4; i += gsz) {     // Wo1p/Wg1p (N=32, nb*16+kt)
        int n = i >> 7, k = (i & 127) * 4;
        size_t dst = ((size_t)(n >> 4) * 16 + (k >> 5)) * 512 + ((k >> 3) & 3) * 128 + (n & 15) * 8 + (k & 4);
        int lo = __builtin_amdgcn_cvt_pk_fp8_f32(Wo1[(size_t)(k+0)*32+n], Wo1[(size_t)(k+1)*32+n], 0, false);
        int pk = __builtin_amdgcn_cvt_pk_fp8_f32(Wo1[(size_t)(k+2)*32+n], Wo1[(size_t)(k+3)*32+n], lo, true);
        *(int*)(Wo1p + dst) = pk;
        lo = __builtin_amdgcn_cvt_pk_fp8_f32(Wg1[(size_t)(k+0)*32+n], Wg1[(size_t)(k+1)*32+n], 0, false);
        pk = __builtin_amdgcn_cvt_pk_fp8_f32(Wg1[(size_t)(k+2)*32+n], Wg1[(size_t)(k+3)*32+n], lo, true);
        *(int*)(Wg1p + dst) = pk;
    }
    for (size_t i = tid; i < 4096ull * 256; i += gsz) {       // Wit[n][k] bf16
        size_t n = i >> 8, k = i & 255;
        float v = (n < 1024) ? Whi[k * 1024 + n]
                : (n < 2048) ? Wci[k * 1024 + (n - 1024)]
                             : Wih0[(1 + k) * 2048 + (n - 2048)];
        Wit[i] = __float2bfloat16(v);
    }
}

// ---------------------------------------------------------------------------
// Init GEMM (bf16): h stored fp8 plain [b][512], c f32, ctxg bf16 [b][j][4g].
// ---------------------------------------------------------------------------
__global__ void __launch_bounds__(256)
k_init(const bf16* __restrict__ efb, const bf16* __restrict__ ctxb,
       const bf16* __restrict__ Wit,
       const float* __restrict__ bh,  const float* __restrict__ bc,
       const float* __restrict__ bi0, const float* __restrict__ bh0,
       u8* __restrict__ h0, u8* __restrict__ h1,
       float* __restrict__ c0, float* __restrict__ c1,
       bf16* __restrict__ ctxg)
{
    const int t = threadIdx.x, lane = t & 63, w = t >> 6;
    const int wr = w >> 1, wc = w & 1;
    const int lq = lane >> 4, ln = lane & 15;
    const int m0 = blockIdx.x * 128, n0 = blockIdx.y * 64;
    const bf16* A = (n0 < 2048) ? efb : ctxb;

    f32x4 zero = {0.f, 0.f, 0.f, 0.f};
    f32x4 acc[4][2];
#pragma unroll
    for (int r = 0; r < 4; ++r)
#pragma unroll
        for (int c = 0; c < 2; ++c) acc[r][c] = zero;

    for (int k0 = 0; k0 < 256; k0 += 32) {
        short8 af[4];
#pragma unroll
        for (int r = 0; r < 4; ++r)
            af[r] = *(const short8*)(A + (size_t)(m0 + wr * 64 + r * 16 + ln) * 256 + k0 + lq * 8);
#pragma unroll
        for (int c = 0; c < 2; ++c) {
            short8 bv = *(const short8*)(Wit + (size_t)(n0 + wc * 32 + c * 16 + ln) * 256 + k0 + lq * 8);
#pragma unroll
            for (int r = 0; r < 4; ++r)
                acc[r][c] = __builtin_amdgcn_mfma_f32_16x16x32_bf16(af[r], bv, acc[r][c], 0, 0, 0);
        }
    }
#pragma unroll
    for (int r = 0; r < 4; ++r)
#pragma unroll
        for (int c = 0; c < 2; ++c)
#pragma unroll
            for (int e = 0; e < 4; ++e) {
                int b = m0 + wr * 64 + r * 16 + lq * 4 + e;
                int n = n0 + wc * 32 + c * 16 + ln;
                float v = acc[r][c][e];
                if (n < 1024) {
                    v += bh[n];
                    if (n < 512) h0[(size_t)b * 512 + n]       = f2fp8(v);
                    else         h1[(size_t)b * 512 + n - 512] = f2fp8(v);
                } else if (n < 2048) {
                    int m = n - 1024; v += bc[m];
                    if (m < 512) c0[(size_t)b * 512 + m]       = v;
                    else         c1[(size_t)b * 512 + m - 512] = v;
                } else {
                    int j = n - 2048;
                    ctxg[(size_t)b * 2048 + (j & 511) * 4 + (j >> 9)] =
                        __float2bfloat16(v + bi0[j] + bh0[j]);
                }
            }
}

// h-LDS B-frag read (B[k][b=ln]): row=ln, chunk c=4kt+lq, swizzle c^ln (4-bit)
__device__ __forceinline__ long hread(const u8* buf, int ln, int lq, int kt) {
    int c = (kt << 2) + lq;
    return *(const long*)(buf + ln * 512 + ((c ^ ln) << 3));
}

// per-wave weight stage: copy the wave's 8 KB kt-region into its ring slot
__device__ __forceinline__ void stageW(const u8* __restrict__ Wp, int w, int kt,
                                       u8* slot, int lane) {
    const u8* src = Wp + ((size_t)(kt * 8 + w) << 13) + lane * 16;
#pragma unroll
    for (int i = 0; i < 8; ++i)
        gload16(src + i * 1024, slot + i * 1024);
}

// ---------------------------------------------------------------------------
// Persistent T-loop kernel. 256 WGs x 512 thr (16 rows x all 2048 cols/WG,
// zero inter-WG deps). Weights stream through PER-WAVE private 2-slot LDS
// rings via global_load_lds + counted vmcnt (no barriers in K-loop, no VGPR
// cost for prefetch). h single-buffered in LDS; c in regs; ctxg/biases
// re-read from L2 per step.
// ---------------------------------------------------------------------------
__global__ void __launch_bounds__(512, 1)
k_loop(const u8* __restrict__ h0i, const u8* __restrict__ h1i,
       const u8* __restrict__ W0p, const u8* __restrict__ W1p,
       const u8* __restrict__ Wo1p, const u8* __restrict__ Wg1p,
       const bf16* __restrict__ ctxg, const float* __restrict__ ii,
       const float* __restrict__ w0row,
       const float* __restrict__ bi1, const float* __restrict__ bh1,
       const float* __restrict__ bo1, const float* __restrict__ Wo2,
       const float* __restrict__ bo2,
       const float* __restrict__ bg1, const float* __restrict__ Wg2,
       const float* __restrict__ bg2,
       const float* __restrict__ c0g, const float* __restrict__ c1g,
       float* __restrict__ out)
{
    __shared__ u8 h0L[8192];
    __shared__ u8 h1L[8192];
    __shared__ u8 Wring[8][2][8192];     // per-wave private 2-slot ring
    __shared__ float sit[16];
    __shared__ float spart[16][2];

    const int t = threadIdx.x, lane = t & 63, w = t >> 6;
    const int ln = lane & 15, lq = lane >> 4;
    const int m0 = blockIdx.x * 16;
    const int b = m0 + ln;
    f32x4 zero = {0.f, 0.f, 0.f, 0.f};

    // ---- prologue: h-init -> LDS (swizzled chunk^row)
#pragma unroll
    for (int i = 0; i < 2; ++i) {
        int cid = i * 512 + t;
        int row = cid >> 6, c = cid & 63;
        long v0 = *(const long*)(h0i + (size_t)(m0 + row) * 512 + c * 8);
        long v1 = *(const long*)(h1i + (size_t)(m0 + row) * 512 + c * 8);
        int pc = row * 512 + ((c ^ row) << 3);
        *(long*)(&h0L[pc]) = v0;
        *(long*)(&h1L[pc]) = v1;
    }
    // ---- per-thread c state at (b=ln, jl=(w*4+jc)*16+lq*4+e)
    f32x4 cr0[4], cr1[4];
#pragma unroll
    for (int jc = 0; jc < 4; ++jc) {
        int jlb = (w * 4 + jc) * 16 + lq * 4;
        cr0[jc] = *(const f32x4*)(c0g + (size_t)b * 512 + jlb);
        cr1[jc] = *(const f32x4*)(c1g + (size_t)b * 512 + jlb);
    }
    __syncthreads();

    // intent head: waves 0,1 do j-tiles 0,1; all threads call (barriers inside)
    auto head2 = [&](const u8* Wp, const float* b1, const float* W2, float b2s,
                     bool tosit, float* dst, int stride, int scol) {
        if (w < 2) {
            f32x4 acc = zero;
#pragma unroll
            for (int kt = 0; kt < 16; ++kt) {
                long bf = hread(h1L, ln, lq, kt);
                long af = *(const long*)(Wp + (size_t)(w * 16 + kt) * 512 + lane * 8);
                acc = __builtin_amdgcn_mfma_f32_16x16x32_fp8_fp8(af, bf, acc, 0, 0, 0);
            }
            float v = 0.f;
#pragma unroll
            for (int e = 0; e < 4; ++e) {
                int j = w * 16 + lq * 4 + e;
                v += fmaxf(acc[e] + b1[j], 0.f) * W2[j];
            }
            v += __shfl_xor(v, 16);
            v += __shfl_xor(v, 32);
            if (lq == 0) spart[ln][w] = v;
        }
        __syncthreads();
        if (t < 16) {
            float pv = sigf(spart[t][0] + spart[t][1] + b2s);
            if (tosit) sit[t] = pv;
            if (dst) dst[(size_t)(m0 + t) * stride + scol] = pv;
        }
        __syncthreads();
    };

    for (int s = 0; s < Tsz; ++s) {
        // ---- intent for this step (head of h1_{s-1}); writes out col s-1
        if (s == 0) {
            if (t < 16) sit[t] = ii[m0 + t];
            __syncthreads();
        } else {
            head2(Wo1p, bo1, Wo2, bo2[0], true, out, Tsz, s - 1);
        }
        const float sval = sit[ln];

        // ================= layer 0: G = W0·h0^T, K=512 ====================
        {
            f32x4 acc[4][4];
#pragma unroll
            for (int jc = 0; jc < 4; ++jc)
#pragma unroll
                for (int g = 0; g < 4; ++g) acc[jc][g] = zero;

            WAIT_VM(0);                               // drain stray vmem ops
            stageW(W0p, w, 0, Wring[w][0], lane);
            stageW(W0p, w, 1, Wring[w][1], lane);
#pragma unroll 2
            for (int kt = 0; kt < 16; ++kt) {
                if (kt < 15) { WAIT_VM(8); } else { WAIT_VM(0); }
                long bf = hread(h0L, ln, lq, kt);
                const u8* slot = Wring[w][kt & 1];
#pragma unroll
                for (int q = 0; q < 16; ++q) {
                    long af = *(const long*)(slot + q * 512 + lane * 8);
                    acc[q & 3][q >> 2] = __builtin_amdgcn_mfma_f32_16x16x32_fp8_fp8(
                        af, bf, acc[q & 3][q >> 2], 0, 0, 0);
                }
                if (kt + 2 < 16) {
                    WAIT_LGKM0;                       // slot reads landed
                    stageW(W0p, w, kt + 2, Wring[w][kt & 1], lane);
                }
            }
            // epilogue: cell, hold h0 bytes in regs, then in-place LDS update
            int hold[4];
#pragma unroll
            for (int jc = 0; jc < 4; ++jc) {
                int jlb = (w * 4 + jc) * 16 + lq * 4;
                f32x4 a0v[4];
#pragma unroll
                for (int g = 0; g < 4; ++g) a0v[g] = *(const f32x4*)(w0row + g * 512 + jlb);
                float hv[4];
#pragma unroll
                for (int e = 0; e < 4; ++e) {
                    us4 xgv = *(const us4*)((const unsigned short*)ctxg + (size_t)b * 2048 + (jlb + e) * 4);
                    float pre[4];
#pragma unroll
                    for (int g = 0; g < 4; ++g)
                        pre[g] = acc[jc][g][e] + b2f(xgv[g]) + sval * a0v[g][e];
                    float ig = sigf(pre[0]), fg = sigf(pre[1]);
                    float gg = tanhft(pre[2]), og = sigf(pre[3]);
                    float cn = fg * cr0[jc][e] + ig * gg;
                    cr0[jc][e] = cn;
                    hv[e] = og * tanhft(cn);
                }
                int lo = __builtin_amdgcn_cvt_pk_fp8_f32(hv[0], hv[1], 0, false);
                hold[jc] = __builtin_amdgcn_cvt_pk_fp8_f32(hv[2], hv[3], lo, true);
            }
            __syncthreads();                          // all done reading h0L
#pragma unroll
            for (int jc = 0; jc < 4; ++jc) {
                int c = (w * 4 + jc) * 2 + (lq >> 1);
                *(int*)(h0L + ln * 512 + ((c ^ ln) << 3) + (lq & 1) * 4) = hold[jc];
            }
            WAIT_LGKM0;
            __syncthreads();                          // h0 new visible
        }

        // ====== layer 1: G = W1·[h0;h1]^T, K=1024 (kt>=16 from h1L) =======
        {
            f32x4 acc[4][4];
#pragma unroll
            for (int jc = 0; jc < 4; ++jc)
#pragma unroll
                for (int g = 0; g < 4; ++g) acc[jc][g] = zero;

            WAIT_VM(0);
            stageW(W1p, w, 0, Wring[w][0], lane);
            stageW(W1p, w, 1, Wring[w][1], lane);
#pragma unroll 2
            for (int kt = 0; kt < 32; ++kt) {
                if (kt < 31) { WAIT_VM(8); } else { WAIT_VM(0); }
                long bf = (kt < 16) ? hread(h0L, ln, lq, kt) : hread(h1L, ln, lq, kt - 16);
                const u8* slot = Wring[w][kt & 1];
#pragma unroll
                for (int q = 0; q < 16; ++q) {
                    long af = *(const long*)(slot + q * 512 + lane * 8);
                    acc[q & 3][q >> 2] = __builtin_amdgcn_mfma_f32_16x16x32_fp8_fp8(
                        af, bf, acc[q & 3][q >> 2], 0, 0, 0);
                }
                if (kt + 2 < 32) {
                    WAIT_LGKM0;
                    stageW(W1p, w, kt + 2, Wring[w][kt & 1], lane);
                }
            }
            int hold[4];
#pragma unroll
            for (int jc = 0; jc < 4; ++jc) {
                int jlb = (w * 4 + jc) * 16 + lq * 4;
                f32x4 a1v[4];
#pragma unroll
                for (int g = 0; g < 4; ++g) {
                    f32x4 bv1 = *(const f32x4*)(bi1 + g * 512 + jlb);
                    f32x4 bv2 = *(const f32x4*)(bh1 + g * 512 + jlb);
#pragma unroll
                    for (int e = 0; e < 4; ++e) a1v[g][e] = bv1[e] + bv2[e];
                }
                float hv[4];
#pragma unroll
                for (int e = 0; e < 4; ++e) {
                    float pre[4];
#pragma unroll
                    for (int g = 0; g < 4; ++g) pre[g] = acc[jc][g][e] + a1v[g][e];
                    float ig = sigf(pre[0]), fg = sigf(pre[1]);
                    float gg = tanhft(pre[2]), og = sigf(pre[3]);
                    float cn = fg * cr1[jc][e] + ig * gg;
                    cr1[jc][e] = cn;
                    hv[e] = og * tanhft(cn);
                }
                int lo = __builtin_amdgcn_cvt_pk_fp8_f32(hv[0], hv[1], 0, false);
                hold[jc] = __builtin_amdgcn_cvt_pk_fp8_f32(hv[2], hv[3], lo, true);
            }
            __syncthreads();                          // all done reading h1L
#pragma unroll
            for (int jc = 0; jc < 4; ++jc) {
                int c = (w * 4 + jc) * 2 + (lq >> 1);
                *(int*)(h1L + ln * 512 + ((c ^ ln) << 3) + (lq & 1) * 4) = hold[jc];
            }
            WAIT_LGKM0;
            __syncthreads();                          // h1 new visible
        }
    }

    // ---- final heads on the final h1 (in h1L)
    head2(Wo1p, bo1, Wo2, bo2[0], false, out, Tsz, 44);
    head2(Wg1p, bg1, Wg2, bg2[0], false, out + (size_t)Bsz * Tsz, 1, 0);
}

// ---------------------------------------------------------------------------
extern "C" void kernel_launch(void* const* d_in, const int* in_sizes, int n_in,
                              void* d_out, int out_size, void* d_ws, size_t ws_size,
                              hipStream_t stream)
{
    const float* ef   = (const float*)d_in[0];
    const float* ctx  = (const float*)d_in[1];
    const float* ii   = (const float*)d_in[2];
    const float* Whi  = (const float*)d_in[3];
    const float* bh   = (const float*)d_in[4];
    const float* Wci  = (const float*)d_in[5];
    const float* bc   = (const float*)d_in[6];
    const float* Wih0 = (const float*)d_in[7];
    const float* Whh0 = (const float*)d_in[8];
    const float* bi0  = (const float*)d_in[9];
    const float* bh0  = (const float*)d_in[10];
    const float* Wih1 = (const float*)d_in[11];
    const float* Whh1 = (const float*)d_in[12];
    const float* bi1  = (const float*)d_in[13];
    const float* bh1  = (const float*)d_in[14];
    const float* Wo1  = (const float*)d_in[15];
    const float* bo1  = (const float*)d_in[16];
    const float* Wo2  = (const float*)d_in[17];
    const float* bo2  = (const float*)d_in[18];
    const float* Wg1  = (const float*)d_in[19];
    const float* bg1  = (const float*)d_in[20];
    const float* Wg2  = (const float*)d_in[21];
    const float* bg2  = (const float*)d_in[22];
    float* out = (float*)d_out;

    char* ws = (char*)d_ws;
    size_t off = 0;
    auto take = [&](size_t bytes) -> char* {
        char* pp = ws + off;
        off += (bytes + 255) & ~(size_t)255;
        return pp;
    };
    u8*  W0p     = (u8*)take(2048ull * 512);
    u8*  W1p     = (u8*)take(2048ull * 1024);
    u8*  Wo1p    = (u8*)take(32ull * 512);
    u8*  Wg1p    = (u8*)take(32ull * 512);
    bf16* Wit    = (bf16*)take(4096ull * 256 * 2);
    bf16* efb    = (bf16*)take((size_t)Bsz * Dsz * 2);
    bf16* ctxb   = (bf16*)take((size_t)Bsz * Dsz * 2);
    u8*  h0x     = (u8*)take((size_t)Bsz * Hsz);
    u8*  h1x     = (u8*)take((size_t)Bsz * Hsz);
    float* c0    = (float*)take((size_t)Bsz * Hsz * 4);
    float* c1    = (float*)take((size_t)Bsz * Hsz * 4);
    bf16* ctxg   = (bf16*)take((size_t)Bsz * 2048 * 2);
    (void)ws_size; (void)in_sizes; (void)n_in; (void)out_size;

    k_conv<<<2048, 256, 0, stream>>>(ef, ctx, Whi, Wci, Wih0, Whh0, Wih1, Whh1, Wo1, Wg1,
                                     efb, ctxb, Wit, W0p, W1p, Wo1p, Wg1p);
    k_init<<<dim3(32, 64), 256, 0, stream>>>(efb, ctxb, Wit, bh, bc, bi0, bh0,
                                             h0x, h1x, c0, c1, ctxg);
    k_loop<<<256, 512, 0, stream>>>(h0x, h1x, W0p, W1p, Wo1p, Wg1p,
                                    ctxg, ii, Wih0, bi1, bh1,
                                    bo1, Wo2, bo2, bg1, Wg2, bg2,
                                    c0, c1, out);
}

// Round 14
// 2594.882 us; speedup vs baseline: 6.2371x; 1.0333x over previous
//
#include <hip/hip_runtime.h>
#include <hip/hip_bf16.h>

#define Bsz 4096
#define Dsz 256
#define Hsz 512
#define Tsz 45

typedef __attribute__((ext_vector_type(8))) short short8;
typedef __attribute__((ext_vector_type(4))) float f32x4;
typedef __attribute__((ext_vector_type(4))) unsigned short us4;
using bf16 = __hip_bfloat16;
using u8 = unsigned char;

__device__ __forceinline__ float sigf(float x)   { return 1.0f / (1.0f + __expf(-x)); }
__device__ __forceinline__ float tanhft(float x) { return 1.0f - 2.0f / (__expf(2.0f * x) + 1.0f); }
__device__ __forceinline__ float b2f(unsigned short u) { return __uint_as_float((unsigned)u << 16); }
__device__ __forceinline__ u8 f2fp8(float v) {
    int p = __builtin_amdgcn_cvt_pk_fp8_f32(v, v, 0, false);
    return (u8)(p & 0xff);
}

__device__ __forceinline__ void gload16(const void* g, void* l) {
    __builtin_amdgcn_global_load_lds((const __attribute__((address_space(1))) void*)g,
                                     (__attribute__((address_space(3))) void*)l, 16, 0, 0);
}

#define WAIT_VM(N) asm volatile("s_waitcnt vmcnt(" #N ")" ::: "memory")

// ---------------------------------------------------------------------------
// Weight convert/pack (one-shot, identical to R12/R13 — proven numerics).
// fp8 weights in (kt, wave, q) blocked 512 B fragment blocks:
// block id = (kt*8 + wv)*16 + q, q = g*4 + jc; inside a block byte (n&15,k&31)
// at lq*128+ln*8+(k&7). A wave's 16 frags for one kt = 8 KB contiguous
// (two 4 KB halves: q0..7, q8..15).
// ---------------------------------------------------------------------------
__global__ void k_conv(const float* __restrict__ ef,   const float* __restrict__ ctx,
                       const float* __restrict__ Whi,  const float* __restrict__ Wci,
                       const float* __restrict__ Wih0, const float* __restrict__ Whh0,
                       const float* __restrict__ Wih1, const float* __restrict__ Whh1,
                       const float* __restrict__ Wo1,  const float* __restrict__ Wg1,
                       bf16* __restrict__ efb,  bf16* __restrict__ ctxb,
                       bf16* __restrict__ Wit,  u8* __restrict__ W0p,
                       u8* __restrict__ W1p,  u8* __restrict__ Wo1p,
                       u8* __restrict__ Wg1p)
{
    size_t tid = (size_t)blockIdx.x * blockDim.x + threadIdx.x;
    size_t gsz = (size_t)gridDim.x * blockDim.x;
    for (size_t i = tid; i < (size_t)Bsz * Dsz; i += gsz) {
        efb[i]  = __float2bfloat16(ef[i]);
        ctxb[i] = __float2bfloat16(ctx[i]);
    }
    for (size_t i = tid; i < 2048ull * 512 / 4; i += gsz) {   // W0p <- Whh0^T
        int n = i >> 7, k = (i & 127) * 4;
        int lo = __builtin_amdgcn_cvt_pk_fp8_f32(Whh0[(size_t)(k+0)*2048+n], Whh0[(size_t)(k+1)*2048+n], 0, false);
        int pk = __builtin_amdgcn_cvt_pk_fp8_f32(Whh0[(size_t)(k+2)*2048+n], Whh0[(size_t)(k+3)*2048+n], lo, true);
        int nb = n >> 4;
        size_t blk = (size_t)((k >> 5) * 8 + ((nb >> 2) & 7)) * 16 + ((nb >> 5) * 4 + (nb & 3));
        *(int*)(W0p + blk * 512 + ((k >> 3) & 3) * 128 + (n & 15) * 8 + (k & 4)) = pk;
    }
    for (size_t i = tid; i < 2048ull * 1024 / 4; i += gsz) {  // W1p <- [Wih1;Whh1]^T
        int n = i >> 8, k = (i & 255) * 4;
        float f0, f1, f2, f3;
        if (k < 512) {
            f0 = Wih1[(size_t)(k+0)*2048+n]; f1 = Wih1[(size_t)(k+1)*2048+n];
            f2 = Wih1[(size_t)(k+2)*2048+n]; f3 = Wih1[(size_t)(k+3)*2048+n];
        } else {
            int kk = k - 512;
            f0 = Whh1[(size_t)(kk+0)*2048+n]; f1 = Whh1[(size_t)(kk+1)*2048+n];
            f2 = Whh1[(size_t)(kk+2)*2048+n]; f3 = Whh1[(size_t)(kk+3)*2048+n];
        }
        int lo = __builtin_amdgcn_cvt_pk_fp8_f32(f0, f1, 0, false);
        int pk = __builtin_amdgcn_cvt_pk_fp8_f32(f2, f3, lo, true);
        int nb = n >> 4;
        size_t blk = (size_t)((k >> 5) * 8 + ((nb >> 2) & 7)) * 16 + ((nb >> 5) * 4 + (nb & 3));
        *(int*)(W1p + blk * 512 + ((k >> 3) & 3) * 128 + (n & 15) * 8 + (k & 4)) = pk;
    }
    for (size_t i = tid; i < 32ull * 512 / 4; i += gsz) {     // Wo1p/Wg1p (N=32, nb*16+kt)
        int n = i >> 7, k = (i & 127) * 4;
        size_t dst = ((size_t)(n >> 4) * 16 + (k >> 5)) * 512 + ((k >> 3) & 3) * 128 + (n & 15) * 8 + (k & 4);
        int lo = __builtin_amdgcn_cvt_pk_fp8_f32(Wo1[(size_t)(k+0)*32+n], Wo1[(size_t)(k+1)*32+n], 0, false);
        int pk = __builtin_amdgcn_cvt_pk_fp8_f32(Wo1[(size_t)(k+2)*32+n], Wo1[(size_t)(k+3)*32+n], lo, true);
        *(int*)(Wo1p + dst) = pk;
        lo = __builtin_amdgcn_cvt_pk_fp8_f32(Wg1[(size_t)(k+0)*32+n], Wg1[(size_t)(k+1)*32+n], 0, false);
        pk = __builtin_amdgcn_cvt_pk_fp8_f32(Wg1[(size_t)(k+2)*32+n], Wg1[(size_t)(k+3)*32+n], lo, true);
        *(int*)(Wg1p + dst) = pk;
    }
    for (size_t i = tid; i < 4096ull * 256; i += gsz) {       // Wit[n][k] bf16
        size_t n = i >> 8, k = i & 255;
        float v = (n < 1024) ? Whi[k * 1024 + n]
                : (n < 2048) ? Wci[k * 1024 + (n - 1024)]
                             : Wih0[(1 + k) * 2048 + (n - 2048)];
        Wit[i] = __float2bfloat16(v);
    }
}

// ---------------------------------------------------------------------------
// Init GEMM (bf16): h stored fp8 plain [b][512], c f32, ctxg bf16 [b][j][4g].
// ---------------------------------------------------------------------------
__global__ void __launch_bounds__(256)
k_init(const bf16* __restrict__ efb, const bf16* __restrict__ ctxb,
       const bf16* __restrict__ Wit,
       const float* __restrict__ bh,  const float* __restrict__ bc,
       const float* __restrict__ bi0, const float* __restrict__ bh0,
       u8* __restrict__ h0, u8* __restrict__ h1,
       float* __restrict__ c0, float* __restrict__ c1,
       bf16* __restrict__ ctxg)
{
    const int t = threadIdx.x, lane = t & 63, w = t >> 6;
    const int wr = w >> 1, wc = w & 1;
    const int lq = lane >> 4, ln = lane & 15;
    const int m0 = blockIdx.x * 128, n0 = blockIdx.y * 64;
    const bf16* A = (n0 < 2048) ? efb : ctxb;

    f32x4 zero = {0.f, 0.f, 0.f, 0.f};
    f32x4 acc[4][2];
#pragma unroll
    for (int r = 0; r < 4; ++r)
#pragma unroll
        for (int c = 0; c < 2; ++c) acc[r][c] = zero;

    for (int k0 = 0; k0 < 256; k0 += 32) {
        short8 af[4];
#pragma unroll
        for (int r = 0; r < 4; ++r)
            af[r] = *(const short8*)(A + (size_t)(m0 + wr * 64 + r * 16 + ln) * 256 + k0 + lq * 8);
#pragma unroll
        for (int c = 0; c < 2; ++c) {
            short8 bv = *(const short8*)(Wit + (size_t)(n0 + wc * 32 + c * 16 + ln) * 256 + k0 + lq * 8);
#pragma unroll
            for (int r = 0; r < 4; ++r)
                acc[r][c] = __builtin_amdgcn_mfma_f32_16x16x32_bf16(af[r], bv, acc[r][c], 0, 0, 0);
        }
    }
#pragma unroll
    for (int r = 0; r < 4; ++r)
#pragma unroll
        for (int c = 0; c < 2; ++c)
#pragma unroll
            for (int e = 0; e < 4; ++e) {
                int b = m0 + wr * 64 + r * 16 + lq * 4 + e;
                int n = n0 + wc * 32 + c * 16 + ln;
                float v = acc[r][c][e];
                if (n < 1024) {
                    v += bh[n];
                    if (n < 512) h0[(size_t)b * 512 + n]       = f2fp8(v);
                    else         h1[(size_t)b * 512 + n - 512] = f2fp8(v);
                } else if (n < 2048) {
                    int m = n - 1024; v += bc[m];
                    if (m < 512) c0[(size_t)b * 512 + m]       = v;
                    else         c1[(size_t)b * 512 + m - 512] = v;
                } else {
                    int j = n - 2048;
                    ctxg[(size_t)b * 2048 + (j & 511) * 4 + (j >> 9)] =
                        __float2bfloat16(v + bi0[j] + bh0[j]);
                }
            }
}

// h-LDS B-frag read (B[k][b=ln]): row=ln, chunk c=4kt+lq, swizzle c^ln (4-bit)
__device__ __forceinline__ long hread(const u8* buf, int ln, int lq, int kt) {
    int c = (kt << 2) + lq;
    return *(const long*)(buf + ln * 512 + ((c ^ ln) << 3));
}

// stage one 4 KB half-kt (half h) of the wave's weight stream into ring slot h&3
__device__ __forceinline__ void stageH(const u8* __restrict__ Wp, int w, int h,
                                       u8* Wr, int lane) {
    const u8* src = Wp + ((size_t)((h >> 1) * 8 + w) << 13) + ((size_t)(h & 1) << 12) + lane * 16;
    u8* dst = Wr + ((size_t)(h & 3) << 12);
#pragma unroll
    for (int i = 0; i < 4; ++i)
        gload16(src + i * 1024, dst + i * 1024);
}

// 8 MFMA of one half-kt: q = QB..QB+7 (static acc indices)
template <int QB>
__device__ __forceinline__ void mfma_half(const u8* slot, int lane, long bf,
                                          f32x4 (&acc)[4][4]) {
#pragma unroll
    for (int i = 0; i < 8; ++i) {
        long af = *(const long*)(slot + i * 512 + lane * 8);
        acc[(QB + i) & 3][(QB + i) >> 2] =
            __builtin_amdgcn_mfma_f32_16x16x32_fp8_fp8(af, bf, acc[(QB + i) & 3][(QB + i) >> 2], 0, 0, 0);
    }
}

// ---------------------------------------------------------------------------
// Persistent T-loop kernel. 256 WGs x 512 thr (16 rows x all 2048 cols/WG,
// zero inter-WG deps). Weights stream through PER-WAVE private ring-4 of
// 4 KB half-kt slots via global_load_lds + counted vmcnt(8): 3 slots (12
// loads) permanently in flight, stage issue decoupled from ds_read drain.
// ---------------------------------------------------------------------------
__global__ void __launch_bounds__(512, 1)
k_loop(const u8* __restrict__ h0i, const u8* __restrict__ h1i,
       const u8* __restrict__ W0p, const u8* __restrict__ W1p,
       const u8* __restrict__ Wo1p, const u8* __restrict__ Wg1p,
       const bf16* __restrict__ ctxg, const float* __restrict__ ii,
       const float* __restrict__ w0row,
       const float* __restrict__ bi1, const float* __restrict__ bh1,
       const float* __restrict__ bo1, const float* __restrict__ Wo2,
       const float* __restrict__ bo2,
       const float* __restrict__ bg1, const float* __restrict__ Wg2,
       const float* __restrict__ bg2,
       const float* __restrict__ c0g, const float* __restrict__ c1g,
       float* __restrict__ out)
{
    __shared__ u8 h0L[8192];
    __shared__ u8 h1L[8192];
    __shared__ u8 WringS[8][16384];      // per-wave ring-4 x 4 KB
    __shared__ float sit[16];
    __shared__ float spart[16][2];

    const int t = threadIdx.x, lane = t & 63, w = t >> 6;
    const int ln = lane & 15, lq = lane >> 4;
    const int m0 = blockIdx.x * 16;
    const int b = m0 + ln;
    u8* Wr = WringS[w];
    f32x4 zero = {0.f, 0.f, 0.f, 0.f};

    // ---- prologue: h-init -> LDS (swizzled chunk^row)
#pragma unroll
    for (int i = 0; i < 2; ++i) {
        int cid = i * 512 + t;
        int row = cid >> 6, c = cid & 63;
        long v0 = *(const long*)(h0i + (size_t)(m0 + row) * 512 + c * 8);
        long v1 = *(const long*)(h1i + (size_t)(m0 + row) * 512 + c * 8);
        int pc = row * 512 + ((c ^ row) << 3);
        *(long*)(&h0L[pc]) = v0;
        *(long*)(&h1L[pc]) = v1;
    }
    // ---- per-thread c state at (b=ln, jl=(w*4+jc)*16+lq*4+e)
    f32x4 cr0[4], cr1[4];
#pragma unroll
    for (int jc = 0; jc < 4; ++jc) {
        int jlb = (w * 4 + jc) * 16 + lq * 4;
        cr0[jc] = *(const f32x4*)(c0g + (size_t)b * 512 + jlb);
        cr1[jc] = *(const f32x4*)(c1g + (size_t)b * 512 + jlb);
    }
    __syncthreads();

    // intent head: waves 0,1 do j-tiles 0,1; all threads call (barriers inside)
    auto head2 = [&](const u8* Wp, const float* b1, const float* W2, float b2s,
                     bool tosit, float* dst, int stride, int scol) {
        if (w < 2) {
            f32x4 acc = zero;
#pragma unroll
            for (int kt = 0; kt < 16; ++kt) {
                long bf = hread(h1L, ln, lq, kt);
                long af = *(const long*)(Wp + (size_t)(w * 16 + kt) * 512 + lane * 8);
                acc = __builtin_amdgcn_mfma_f32_16x16x32_fp8_fp8(af, bf, acc, 0, 0, 0);
            }
            float v = 0.f;
#pragma unroll
            for (int e = 0; e < 4; ++e) {
                int j = w * 16 + lq * 4 + e;
                v += fmaxf(acc[e] + b1[j], 0.f) * W2[j];
            }
            v += __shfl_xor(v, 16);
            v += __shfl_xor(v, 32);
            if (lq == 0) spart[ln][w] = v;
        }
        __syncthreads();
        if (t < 16) {
            float pv = sigf(spart[t][0] + spart[t][1] + b2s);
            if (tosit) sit[t] = pv;
            if (dst) dst[(size_t)(m0 + t) * stride + scol] = pv;
        }
        __syncthreads();
    };

    for (int s = 0; s < Tsz; ++s) {
        // ---- intent for this step (head of h1_{s-1}); writes out col s-1
        if (s == 0) {
            if (t < 16) sit[t] = ii[m0 + t];
            __syncthreads();
        } else {
            head2(Wo1p, bo1, Wo2, bo2[0], true, out, Tsz, s - 1);
        }
        const float sval = sit[ln];

        // ================= layer 0: G = W0·h0^T, K=512 (H=32 halves) =======
        {
            f32x4 acc[4][4];
#pragma unroll
            for (int jc = 0; jc < 4; ++jc)
#pragma unroll
                for (int g = 0; g < 4; ++g) acc[jc][g] = zero;

            WAIT_VM(0);
            stageH(W0p, w, 0, Wr, lane);
            stageH(W0p, w, 1, Wr, lane);
            stageH(W0p, w, 2, Wr, lane);
#pragma unroll 2
            for (int kt = 0; kt < 14; ++kt) {
                long bf = hread(h0L, ln, lq, kt);
                WAIT_VM(8);
                mfma_half<0>(Wr + (size_t)((2 * kt) & 3) * 4096, lane, bf, acc);
                stageH(W0p, w, 2 * kt + 3, Wr, lane);
                WAIT_VM(8);
                mfma_half<8>(Wr + (size_t)((2 * kt + 1) & 3) * 4096, lane, bf, acc);
                stageH(W0p, w, 2 * kt + 4, Wr, lane);
            }
            {   // kt = 14
                long bf = hread(h0L, ln, lq, 14);
                WAIT_VM(8);
                mfma_half<0>(Wr + (size_t)(28 & 3) * 4096, lane, bf, acc);
                stageH(W0p, w, 31, Wr, lane);
                WAIT_VM(8);
                mfma_half<8>(Wr + (size_t)(29 & 3) * 4096, lane, bf, acc);
            }
            {   // kt = 15
                long bf = hread(h0L, ln, lq, 15);
                WAIT_VM(4);
                mfma_half<0>(Wr + (size_t)(30 & 3) * 4096, lane, bf, acc);
                WAIT_VM(0);
                mfma_half<8>(Wr + (size_t)(31 & 3) * 4096, lane, bf, acc);
            }
            // epilogue: cell, hold h0 bytes in regs, then in-place LDS update
            int hold[4];
#pragma unroll
            for (int jc = 0; jc < 4; ++jc) {
                int jlb = (w * 4 + jc) * 16 + lq * 4;
                f32x4 a0v[4];
#pragma unroll
                for (int g = 0; g < 4; ++g) a0v[g] = *(const f32x4*)(w0row + g * 512 + jlb);
                float hv[4];
#pragma unroll
                for (int e = 0; e < 4; ++e) {
                    us4 xgv = *(const us4*)((const unsigned short*)ctxg + (size_t)b * 2048 + (jlb + e) * 4);
                    float pre[4];
#pragma unroll
                    for (int g = 0; g < 4; ++g)
                        pre[g] = acc[jc][g][e] + b2f(xgv[g]) + sval * a0v[g][e];
                    float ig = sigf(pre[0]), fg = sigf(pre[1]);
                    float gg = tanhft(pre[2]), og = sigf(pre[3]);
                    float cn = fg * cr0[jc][e] + ig * gg;
                    cr0[jc][e] = cn;
                    hv[e] = og * tanhft(cn);
                }
                int lo = __builtin_amdgcn_cvt_pk_fp8_f32(hv[0], hv[1], 0, false);
                hold[jc] = __builtin_amdgcn_cvt_pk_fp8_f32(hv[2], hv[3], lo, true);
            }
            __syncthreads();                          // all done reading h0L
#pragma unroll
            for (int jc = 0; jc < 4; ++jc) {
                int c = (w * 4 + jc) * 2 + (lq >> 1);
                *(int*)(h0L + ln * 512 + ((c ^ ln) << 3) + (lq & 1) * 4) = hold[jc];
            }
            asm volatile("s_waitcnt lgkmcnt(0)" ::: "memory");
            __syncthreads();                          // h0 new visible
        }

        // ====== layer 1: G = W1·[h0;h1]^T, K=1024 (H=64 halves) ===========
        {
            f32x4 acc[4][4];
#pragma unroll
            for (int jc = 0; jc < 4; ++jc)
#pragma unroll
                for (int g = 0; g < 4; ++g) acc[jc][g] = zero;

            WAIT_VM(0);
            stageH(W1p, w, 0, Wr, lane);
            stageH(W1p, w, 1, Wr, lane);
            stageH(W1p, w, 2, Wr, lane);
#pragma unroll 2
            for (int kt = 0; kt < 16; ++kt) {
                long bf = hread(h0L, ln, lq, kt);
                WAIT_VM(8);
                mfma_half<0>(Wr + (size_t)((2 * kt) & 3) * 4096, lane, bf, acc);
                stageH(W1p, w, 2 * kt + 3, Wr, lane);
                WAIT_VM(8);
                mfma_half<8>(Wr + (size_t)((2 * kt + 1) & 3) * 4096, lane, bf, acc);
                stageH(W1p, w, 2 * kt + 4, Wr, lane);
            }
#pragma unroll 2
            for (int kt = 16; kt < 30; ++kt) {
                long bf = hread(h1L, ln, lq, kt - 16);
                WAIT_VM(8);
                mfma_half<0>(Wr + (size_t)((2 * kt) & 3) * 4096, lane, bf, acc);
                stageH(W1p, w, 2 * kt + 3, Wr, lane);
                WAIT_VM(8);
                mfma_half<8>(Wr + (size_t)((2 * kt + 1) & 3) * 4096, lane, bf, acc);
                stageH(W1p, w, 2 * kt + 4, Wr, lane);
            }
            {   // kt = 30
                long bf = hread(h1L, ln, lq, 14);
                WAIT_VM(8);
                mfma_half<0>(Wr + (size_t)(60 & 3) * 4096, lane, bf, acc);
                stageH(W1p, w, 63, Wr, lane);
                WAIT_VM(8);
                mfma_half<8>(Wr + (size_t)(61 & 3) * 4096, lane, bf, acc);
            }
            {   // kt = 31
                long bf = hread(h1L, ln, lq, 15);
                WAIT_VM(4);
                mfma_half<0>(Wr + (size_t)(62 & 3) * 4096, lane, bf, acc);
                WAIT_VM(0);
                mfma_half<8>(Wr + (size_t)(63 & 3) * 4096, lane, bf, acc);
            }
            int hold[4];
#pragma unroll
            for (int jc = 0; jc < 4; ++jc) {
                int jlb = (w * 4 + jc) * 16 + lq * 4;
                f32x4 a1v[4];
#pragma unroll
                for (int g = 0; g < 4; ++g) {
                    f32x4 bv1 = *(const f32x4*)(bi1 + g * 512 + jlb);
                    f32x4 bv2 = *(const f32x4*)(bh1 + g * 512 + jlb);
#pragma unroll
                    for (int e = 0; e < 4; ++e) a1v[g][e] = bv1[e] + bv2[e];
                }
                float hv[4];
#pragma unroll
                for (int e = 0; e < 4; ++e) {
                    float pre[4];
#pragma unroll
                    for (int g = 0; g < 4; ++g) pre[g] = acc[jc][g][e] + a1v[g][e];
                    float ig = sigf(pre[0]), fg = sigf(pre[1]);
                    float gg = tanhft(pre[2]), og = sigf(pre[3]);
                    float cn = fg * cr1[jc][e] + ig * gg;
                    cr1[jc][e] = cn;
                    hv[e] = og * tanhft(cn);
                }
                int lo = __builtin_amdgcn_cvt_pk_fp8_f32(hv[0], hv[1], 0, false);
                hold[jc] = __builtin_amdgcn_cvt_pk_fp8_f32(hv[2], hv[3], lo, true);
            }
            __syncthreads();                          // all done reading h1L
#pragma unroll
            for (int jc = 0; jc < 4; ++jc) {
                int c = (w * 4 + jc) * 2 + (lq >> 1);
                *(int*)(h1L + ln * 512 + ((c ^ ln) << 3) + (lq & 1) * 4) = hold[jc];
            }
            asm volatile("s_waitcnt lgkmcnt(0)" ::: "memory");
            __syncthreads();                          // h1 new visible
        }
    }

    // ---- final heads on the final h1 (in h1L)
    head2(Wo1p, bo1, Wo2, bo2[0], false, out, Tsz, 44);
    head2(Wg1p, bg1, Wg2, bg2[0], false, out + (size_t)Bsz * Tsz, 1, 0);
}

// ---------------------------------------------------------------------------
extern "C" void kernel_launch(void* const* d_in, const int* in_sizes, int n_in,
                              void* d_out, int out_size, void* d_ws, size_t ws_size,
                              hipStream_t stream)
{
    const float* ef   = (const float*)d_in[0];
    const float* ctx  = (const float*)d_in[1];
    const float* ii   = (const float*)d_in[2];
    const float* Whi  = (const float*)d_in[3];
    const float* bh   = (const float*)d_in[4];
    const float* Wci  = (const float*)d_in[5];
    const float* bc   = (const float*)d_in[6];
    const float* Wih0 = (const float*)d_in[7];
    const float* Whh0 = (const float*)d_in[8];
    const float* bi0  = (const float*)d_in[9];
    const float* bh0  = (const float*)d_in[10];
    const float* Wih1 = (const float*)d_in[11];
    const float* Whh1 = (const float*)d_in[12];
    const float* bi1  = (const float*)d_in[13];
    const float* bh1  = (const float*)d_in[14];
    const float* Wo1  = (const float*)d_in[15];
    const float* bo1  = (const float*)d_in[16];
    const float* Wo2  = (const float*)d_in[17];
    const float* bo2  = (const float*)d_in[18];
    const float* Wg1  = (const float*)d_in[19];
    const float* bg1  = (const float*)d_in[20];
    const float* Wg2  = (const float*)d_in[21];
    const float* bg2  = (const float*)d_in[22];
    float* out = (float*)d_out;

    char* ws = (char*)d_ws;
    size_t off = 0;
    auto take = [&](size_t bytes) -> char* {
        char* pp = ws + off;
        off += (bytes + 255) & ~(size_t)255;
        return pp;
    };
    u8*  W0p     = (u8*)take(2048ull * 512);
    u8*  W1p     = (u8*)take(2048ull * 1024);
    u8*  Wo1p    = (u8*)take(32ull * 512);
    u8*  Wg1p    = (u8*)take(32ull * 512);
    bf16* Wit    = (bf16*)take(4096ull * 256 * 2);
    bf16* efb    = (bf16*)take((size_t)Bsz * Dsz * 2);
    bf16* ctxb   = (bf16*)take((size_t)Bsz * Dsz * 2);
    u8*  h0x     = (u8*)take((size_t)Bsz * Hsz);
    u8*  h1x     = (u8*)take((size_t)Bsz * Hsz);
    float* c0    = (float*)take((size_t)Bsz * Hsz * 4);
    float* c1    = (float*)take((size_t)Bsz * Hsz * 4);
    bf16* ctxg   = (bf16*)take((size_t)Bsz * 2048 * 2);
    (void)ws_size; (void)in_sizes; (void)n_in; (void)out_size;

    k_conv<<<2048, 256, 0, stream>>>(ef, ctx, Whi, Wci, Wih0, Whh0, Wih1, Whh1, Wo1, Wg1,
                                     efb, ctxb, Wit, W0p, W1p, Wo1p, Wg1p);
    k_init<<<dim3(32, 64), 256, 0, stream>>>(efb, ctxb, Wit, bh, bc, bi0, bh0,
                                             h0x, h1x, c0, c1, ctxg);
    k_loop<<<256, 512, 0, stream>>>(h0x, h1x, W0p, W1p, Wo1p, Wg1p,
                                    ctxg, ii, Wih0, bi1, bh1,
                                    bo1, Wo2, bo2, bg1, Wg2, bg2,
                                    c0, c1, out);
}

// Round 15
// 2464.766 us; speedup vs baseline: 6.5664x; 1.0528x over previous
//
#include <hip/hip_runtime.h>
#include <hip/hip_bf16.h>

#define Bsz 4096
#define Dsz 256
#define Hsz 512
#define Tsz 45

typedef __attribute__((ext_vector_type(8))) short short8;
typedef __attribute__((ext_vector_type(4))) float f32x4;
typedef __attribute__((ext_vector_type(4))) unsigned short us4;
using bf16 = __hip_bfloat16;
using u8 = unsigned char;

__device__ __forceinline__ float sigf(float x)   { return 1.0f / (1.0f + __expf(-x)); }
__device__ __forceinline__ float tanhft(float x) { return 1.0f - 2.0f / (__expf(2.0f * x) + 1.0f); }
__device__ __forceinline__ float b2f(unsigned short u) { return __uint_as_float((unsigned)u << 16); }
__device__ __forceinline__ u8 f2fp8(float v) {
    int p = __builtin_amdgcn_cvt_pk_fp8_f32(v, v, 0, false);
    return (u8)(p & 0xff);
}

__device__ __forceinline__ void gload16(const void* g, void* l) {
    __builtin_amdgcn_global_load_lds((const __attribute__((address_space(1))) void*)g,
                                     (__attribute__((address_space(3))) void*)l, 16, 0, 0);
}

#define WAIT_VM(N) asm volatile("s_waitcnt vmcnt(" #N ")" ::: "memory")

// ---------------------------------------------------------------------------
// Weight convert/pack (one-shot, identical to R12-R14 — proven numerics).
// ---------------------------------------------------------------------------
__global__ void k_conv(const float* __restrict__ ef,   const float* __restrict__ ctx,
                       const float* __restrict__ Whi,  const float* __restrict__ Wci,
                       const float* __restrict__ Wih0, const float* __restrict__ Whh0,
                       const float* __restrict__ Wih1, const float* __restrict__ Whh1,
                       const float* __restrict__ Wo1,  const float* __restrict__ Wg1,
                       bf16* __restrict__ efb,  bf16* __restrict__ ctxb,
                       bf16* __restrict__ Wit,  u8* __restrict__ W0p,
                       u8* __restrict__ W1p,  u8* __restrict__ Wo1p,
                       u8* __restrict__ Wg1p)
{
    size_t tid = (size_t)blockIdx.x * blockDim.x + threadIdx.x;
    size_t gsz = (size_t)gridDim.x * blockDim.x;
    for (size_t i = tid; i < (size_t)Bsz * Dsz; i += gsz) {
        efb[i]  = __float2bfloat16(ef[i]);
        ctxb[i] = __float2bfloat16(ctx[i]);
    }
    for (size_t i = tid; i < 2048ull * 512 / 4; i += gsz) {   // W0p <- Whh0^T
        int n = i >> 7, k = (i & 127) * 4;
        int lo = __builtin_amdgcn_cvt_pk_fp8_f32(Whh0[(size_t)(k+0)*2048+n], Whh0[(size_t)(k+1)*2048+n], 0, false);
        int pk = __builtin_amdgcn_cvt_pk_fp8_f32(Whh0[(size_t)(k+2)*2048+n], Whh0[(size_t)(k+3)*2048+n], lo, true);
        int nb = n >> 4;
        size_t blk = (size_t)((k >> 5) * 8 + ((nb >> 2) & 7)) * 16 + ((nb >> 5) * 4 + (nb & 3));
        *(int*)(W0p + blk * 512 + ((k >> 3) & 3) * 128 + (n & 15) * 8 + (k & 4)) = pk;
    }
    for (size_t i = tid; i < 2048ull * 1024 / 4; i += gsz) {  // W1p <- [Wih1;Whh1]^T
        int n = i >> 8, k = (i & 255) * 4;
        float f0, f1, f2, f3;
        if (k < 512) {
            f0 = Wih1[(size_t)(k+0)*2048+n]; f1 = Wih1[(size_t)(k+1)*2048+n];
            f2 = Wih1[(size_t)(k+2)*2048+n]; f3 = Wih1[(size_t)(k+3)*2048+n];
        } else {
            int kk = k - 512;
            f0 = Whh1[(size_t)(kk+0)*2048+n]; f1 = Whh1[(size_t)(kk+1)*2048+n];
            f2 = Whh1[(size_t)(kk+2)*2048+n]; f3 = Whh1[(size_t)(kk+3)*2048+n];
        }
        int lo = __builtin_amdgcn_cvt_pk_fp8_f32(f0, f1, 0, false);
        int pk = __builtin_amdgcn_cvt_pk_fp8_f32(f2, f3, lo, true);
        int nb = n >> 4;
        size_t blk = (size_t)((k >> 5) * 8 + ((nb >> 2) & 7)) * 16 + ((nb >> 5) * 4 + (nb & 3));
        *(int*)(W1p + blk * 512 + ((k >> 3) & 3) * 128 + (n & 15) * 8 + (k & 4)) = pk;
    }
    for (size_t i = tid; i < 32ull * 512 / 4; i += gsz) {     // Wo1p/Wg1p (N=32, nb*16+kt)
        int n = i >> 7, k = (i & 127) * 4;
        size_t dst = ((size_t)(n >> 4) * 16 + (k >> 5)) * 512 + ((k >> 3) & 3) * 128 + (n & 15) * 8 + (k & 4);
        int lo = __builtin_amdgcn_cvt_pk_fp8_f32(Wo1[(size_t)(k+0)*32+n], Wo1[(size_t)(k+1)*32+n], 0, false);
        int pk = __builtin_amdgcn_cvt_pk_fp8_f32(Wo1[(size_t)(k+2)*32+n], Wo1[(size_t)(k+3)*32+n], lo, true);
        *(int*)(Wo1p + dst) = pk;
        lo = __builtin_amdgcn_cvt_pk_fp8_f32(Wg1[(size_t)(k+0)*32+n], Wg1[(size_t)(k+1)*32+n], 0, false);
        pk = __builtin_amdgcn_cvt_pk_fp8_f32(Wg1[(size_t)(k+2)*32+n], Wg1[(size_t)(k+3)*32+n], lo, true);
        *(int*)(Wg1p + dst) = pk;
    }
    for (size_t i = tid; i < 4096ull * 256; i += gsz) {       // Wit[n][k] bf16
        size_t n = i >> 8, k = i & 255;
        float v = (n < 1024) ? Whi[k * 1024 + n]
                : (n < 2048) ? Wci[k * 1024 + (n - 1024)]
                             : Wih0[(1 + k) * 2048 + (n - 2048)];
        Wit[i] = __float2bfloat16(v);
    }
}

// ---------------------------------------------------------------------------
// Init GEMM (bf16): h stored fp8 plain [b][512], c f32, ctxg bf16 [b][j][4g].
// ---------------------------------------------------------------------------
__global__ void __launch_bounds__(256)
k_init(const bf16* __restrict__ efb, const bf16* __restrict__ ctxb,
       const bf16* __restrict__ Wit,
       const float* __restrict__ bh,  const float* __restrict__ bc,
       const float* __restrict__ bi0, const float* __restrict__ bh0,
       u8* __restrict__ h0, u8* __restrict__ h1,
       float* __restrict__ c0, float* __restrict__ c1,
       bf16* __restrict__ ctxg)
{
    const int t = threadIdx.x, lane = t & 63, w = t >> 6;
    const int wr = w >> 1, wc = w & 1;
    const int lq = lane >> 4, ln = lane & 15;
    const int m0 = blockIdx.x * 128, n0 = blockIdx.y * 64;
    const bf16* A = (n0 < 2048) ? efb : ctxb;

    f32x4 zero = {0.f, 0.f, 0.f, 0.f};
    f32x4 acc[4][2];
#pragma unroll
    for (int r = 0; r < 4; ++r)
#pragma unroll
        for (int c = 0; c < 2; ++c) acc[r][c] = zero;

    for (int k0 = 0; k0 < 256; k0 += 32) {
        short8 af[4];
#pragma unroll
        for (int r = 0; r < 4; ++r)
            af[r] = *(const short8*)(A + (size_t)(m0 + wr * 64 + r * 16 + ln) * 256 + k0 + lq * 8);
#pragma unroll
        for (int c = 0; c < 2; ++c) {
            short8 bv = *(const short8*)(Wit + (size_t)(n0 + wc * 32 + c * 16 + ln) * 256 + k0 + lq * 8);
#pragma unroll
            for (int r = 0; r < 4; ++r)
                acc[r][c] = __builtin_amdgcn_mfma_f32_16x16x32_bf16(af[r], bv, acc[r][c], 0, 0, 0);
        }
    }
#pragma unroll
    for (int r = 0; r < 4; ++r)
#pragma unroll
        for (int c = 0; c < 2; ++c)
#pragma unroll
            for (int e = 0; e < 4; ++e) {
                int b = m0 + wr * 64 + r * 16 + lq * 4 + e;
                int n = n0 + wc * 32 + c * 16 + ln;
                float v = acc[r][c][e];
                if (n < 1024) {
                    v += bh[n];
                    if (n < 512) h0[(size_t)b * 512 + n]       = f2fp8(v);
                    else         h1[(size_t)b * 512 + n - 512] = f2fp8(v);
                } else if (n < 2048) {
                    int m = n - 1024; v += bc[m];
                    if (m < 512) c0[(size_t)b * 512 + m]       = v;
                    else         c1[(size_t)b * 512 + m - 512] = v;
                } else {
                    int j = n - 2048;
                    ctxg[(size_t)b * 2048 + (j & 511) * 4 + (j >> 9)] =
                        __float2bfloat16(v + bi0[j] + bh0[j]);
                }
            }
}

// h-LDS B-frag read (B[k][b=ln]): row=ln, chunk c=4kt+lq, swizzle c^ln (4-bit)
__device__ __forceinline__ long hread(const u8* buf, int ln, int lq, int kt) {
    int c = (kt << 2) + lq;
    return *(const long*)(buf + ln * 512 + ((c ^ ln) << 3));
}

// stage one 4 KB half-kt (half h) of the wave's weight stream into ring slot h&3
__device__ __forceinline__ void stageH(const u8* __restrict__ Wp, int w, int h,
                                       u8* Wr, int lane) {
    const u8* src = Wp + ((size_t)((h >> 1) * 8 + w) << 13) + ((size_t)(h & 1) << 12) + lane * 16;
    u8* dst = Wr + ((size_t)(h & 3) << 12);
#pragma unroll
    for (int i = 0; i < 4; ++i)
        gload16(src + i * 1024, dst + i * 1024);
}

// 8 MFMA of one half-kt: q = QB..QB+7 (static acc indices)
template <int QB>
__device__ __forceinline__ void mfma_half(const u8* slot, int lane, long bf,
                                          f32x4 (&acc)[4][4]) {
#pragma unroll
    for (int i = 0; i < 8; ++i) {
        long af = *(const long*)(slot + i * 512 + lane * 8);
        acc[(QB + i) & 3][(QB + i) >> 2] =
            __builtin_amdgcn_mfma_f32_16x16x32_fp8_fp8(af, bf, acc[(QB + i) & 3][(QB + i) >> 2], 0, 0, 0);
    }
}

// ---------------------------------------------------------------------------
// Persistent T-loop kernel. 256 WGs x 512 thr (16 rows x all 2048 cols/WG).
// Weight stream: per-wave ring-4 of 4 KB half-kt LDS slots, counted vmcnt(8).
// All non-weight state RESIDENT: ctxg in regs, biases in LDS (bf16), c in
// regs, h in LDS -> the only per-step global traffic is the weight stream
// (L2 stays clean). Intent head overlapped with layer-0's stage prologue.
// ---------------------------------------------------------------------------
__global__ void __launch_bounds__(512, 1)
k_loop(const u8* __restrict__ h0i, const u8* __restrict__ h1i,
       const u8* __restrict__ W0p, const u8* __restrict__ W1p,
       const u8* __restrict__ Wo1p, const u8* __restrict__ Wg1p,
       const bf16* __restrict__ ctxg, const float* __restrict__ ii,
       const float* __restrict__ w0row,
       const float* __restrict__ bi1, const float* __restrict__ bh1,
       const float* __restrict__ bo1, const float* __restrict__ Wo2,
       const float* __restrict__ bo2,
       const float* __restrict__ bg1, const float* __restrict__ Wg2,
       const float* __restrict__ bg2,
       const float* __restrict__ c0g, const float* __restrict__ c1g,
       float* __restrict__ out)
{
    __shared__ u8 h0L[8192];
    __shared__ u8 h1L[8192];
    __shared__ u8 WringS[8][16384];      // per-wave ring-4 x 4 KB
    __shared__ unsigned short a0Lb[2048];    // w0row as bf16
    __shared__ unsigned short a1Lb[2048];    // bi1+bh1 as bf16
    __shared__ float sit[16];
    __shared__ float spart[16][2];

    const int t = threadIdx.x, lane = t & 63, w = t >> 6;
    const int ln = lane & 15, lq = lane >> 4;
    const int m0 = blockIdx.x * 16;
    const int b = m0 + ln;
    u8* Wr = WringS[w];
    f32x4 zero = {0.f, 0.f, 0.f, 0.f};

    // ---- prologue: h-init -> LDS (swizzled chunk^row); biases -> LDS bf16
#pragma unroll
    for (int i = 0; i < 2; ++i) {
        int cid = i * 512 + t;
        int row = cid >> 6, c = cid & 63;
        long v0 = *(const long*)(h0i + (size_t)(m0 + row) * 512 + c * 8);
        long v1 = *(const long*)(h1i + (size_t)(m0 + row) * 512 + c * 8);
        int pc = row * 512 + ((c ^ row) << 3);
        *(long*)(&h0L[pc]) = v0;
        *(long*)(&h1L[pc]) = v1;
    }
#pragma unroll
    for (int i = 0; i < 4; ++i) {
        int idx = i * 512 + t;
        a0Lb[idx] = (unsigned short)(__bfloat16_as_ushort(__float2bfloat16(w0row[idx])));
        a1Lb[idx] = (unsigned short)(__bfloat16_as_ushort(__float2bfloat16(bi1[idx] + bh1[idx])));
    }
    // ---- per-thread resident state: c and ctxg at (b=ln, jl=(w*4+jc)*16+lq*4+e)
    f32x4 cr0[4], cr1[4];
    us4 xg[4][4];
#pragma unroll
    for (int jc = 0; jc < 4; ++jc) {
        int jlb = (w * 4 + jc) * 16 + lq * 4;
        cr0[jc] = *(const f32x4*)(c0g + (size_t)b * 512 + jlb);
        cr1[jc] = *(const f32x4*)(c1g + (size_t)b * 512 + jlb);
#pragma unroll
        for (int e = 0; e < 4; ++e)
            xg[jc][e] = *(const us4*)((const unsigned short*)ctxg + (size_t)b * 2048 + (jlb + e) * 4);
    }
    __syncthreads();

    // intent head: waves 0,1 do j-tiles 0,1; all threads call (barriers inside)
    auto head2 = [&](const u8* Wp, const float* b1, const float* W2, float b2s,
                     bool tosit, float* dst, int stride, int scol) {
        if (w < 2) {
            f32x4 acc = zero;
#pragma unroll
            for (int kt = 0; kt < 16; ++kt) {
                long bf = hread(h1L, ln, lq, kt);
                long af = *(const long*)(Wp + (size_t)(w * 16 + kt) * 512 + lane * 8);
                acc = __builtin_amdgcn_mfma_f32_16x16x32_fp8_fp8(af, bf, acc, 0, 0, 0);
            }
            float v = 0.f;
#pragma unroll
            for (int e = 0; e < 4; ++e) {
                int j = w * 16 + lq * 4 + e;
                v += fmaxf(acc[e] + b1[j], 0.f) * W2[j];
            }
            v += __shfl_xor(v, 16);
            v += __shfl_xor(v, 32);
            if (lq == 0) spart[ln][w] = v;
        }
        __syncthreads();
        if (t < 16) {
            float pv = sigf(spart[t][0] + spart[t][1] + b2s);
            if (tosit) sit[t] = pv;
            if (dst) dst[(size_t)(m0 + t) * stride + scol] = pv;
        }
        __syncthreads();
    };

    for (int s = 0; s < Tsz; ++s) {
        // ---- issue layer-0's first 3 weight slots, then compute the intent
        // head while they fly (T14: head compute hides stage latency)
        WAIT_VM(0);
        stageH(W0p, w, 0, Wr, lane);
        stageH(W0p, w, 1, Wr, lane);
        stageH(W0p, w, 2, Wr, lane);

        if (s == 0) {
            if (t < 16) sit[t] = ii[m0 + t];
            __syncthreads();
        } else {
            head2(Wo1p, bo1, Wo2, bo2[0], true, out, Tsz, s - 1);
        }
        const float sval = sit[ln];

        // ================= layer 0: G = W0·h0^T, K=512 (H=32 halves) =======
        {
            f32x4 acc[4][4];
#pragma unroll
            for (int jc = 0; jc < 4; ++jc)
#pragma unroll
                for (int g = 0; g < 4; ++g) acc[jc][g] = zero;

#pragma unroll 2
            for (int kt = 0; kt < 14; ++kt) {
                long bf = hread(h0L, ln, lq, kt);
                WAIT_VM(8);
                mfma_half<0>(Wr + (size_t)((2 * kt) & 3) * 4096, lane, bf, acc);
                stageH(W0p, w, 2 * kt + 3, Wr, lane);
                WAIT_VM(8);
                mfma_half<8>(Wr + (size_t)((2 * kt + 1) & 3) * 4096, lane, bf, acc);
                stageH(W0p, w, 2 * kt + 4, Wr, lane);
            }
            {   // kt = 14
                long bf = hread(h0L, ln, lq, 14);
                WAIT_VM(8);
                mfma_half<0>(Wr + (size_t)(28 & 3) * 4096, lane, bf, acc);
                stageH(W0p, w, 31, Wr, lane);
                WAIT_VM(8);
                mfma_half<8>(Wr + (size_t)(29 & 3) * 4096, lane, bf, acc);
            }
            {   // kt = 15
                long bf = hread(h0L, ln, lq, 15);
                WAIT_VM(4);
                mfma_half<0>(Wr + (size_t)(30 & 3) * 4096, lane, bf, acc);
                WAIT_VM(0);
                mfma_half<8>(Wr + (size_t)(31 & 3) * 4096, lane, bf, acc);
            }
            // epilogue: cell from resident state only (no global loads)
            int hold[4];
#pragma unroll
            for (int jc = 0; jc < 4; ++jc) {
                int jlb = (w * 4 + jc) * 16 + lq * 4;
                us4 a0v[4];
#pragma unroll
                for (int g = 0; g < 4; ++g) a0v[g] = *(const us4*)(a0Lb + g * 512 + jlb);
                float hv[4];
#pragma unroll
                for (int e = 0; e < 4; ++e) {
                    float pre[4];
#pragma unroll
                    for (int g = 0; g < 4; ++g)
                        pre[g] = acc[jc][g][e] + b2f(xg[jc][e][g]) + sval * b2f(a0v[g][e]);
                    float ig = sigf(pre[0]), fg = sigf(pre[1]);
                    float gg = tanhft(pre[2]), og = sigf(pre[3]);
                    float cn = fg * cr0[jc][e] + ig * gg;
                    cr0[jc][e] = cn;
                    hv[e] = og * tanhft(cn);
                }
                int lo = __builtin_amdgcn_cvt_pk_fp8_f32(hv[0], hv[1], 0, false);
                hold[jc] = __builtin_amdgcn_cvt_pk_fp8_f32(hv[2], hv[3], lo, true);
            }
            __syncthreads();                          // all done reading h0L
#pragma unroll
            for (int jc = 0; jc < 4; ++jc) {
                int c = (w * 4 + jc) * 2 + (lq >> 1);
                *(int*)(h0L + ln * 512 + ((c ^ ln) << 3) + (lq & 1) * 4) = hold[jc];
            }
            asm volatile("s_waitcnt lgkmcnt(0)" ::: "memory");
            __syncthreads();                          // h0 new visible
        }

        // ====== layer 1: G = W1·[h0;h1]^T, K=1024 (H=64 halves) ===========
        {
            f32x4 acc[4][4];
#pragma unroll
            for (int jc = 0; jc < 4; ++jc)
#pragma unroll
                for (int g = 0; g < 4; ++g) acc[jc][g] = zero;

            WAIT_VM(0);
            stageH(W1p, w, 0, Wr, lane);
            stageH(W1p, w, 1, Wr, lane);
            stageH(W1p, w, 2, Wr, lane);
#pragma unroll 2
            for (int kt = 0; kt < 16; ++kt) {
                long bf = hread(h0L, ln, lq, kt);
                WAIT_VM(8);
                mfma_half<0>(Wr + (size_t)((2 * kt) & 3) * 4096, lane, bf, acc);
                stageH(W1p, w, 2 * kt + 3, Wr, lane);
                WAIT_VM(8);
                mfma_half<8>(Wr + (size_t)((2 * kt + 1) & 3) * 4096, lane, bf, acc);
                stageH(W1p, w, 2 * kt + 4, Wr, lane);
            }
#pragma unroll 2
            for (int kt = 16; kt < 30; ++kt) {
                long bf = hread(h1L, ln, lq, kt - 16);
                WAIT_VM(8);
                mfma_half<0>(Wr + (size_t)((2 * kt) & 3) * 4096, lane, bf, acc);
                stageH(W1p, w, 2 * kt + 3, Wr, lane);
                WAIT_VM(8);
                mfma_half<8>(Wr + (size_t)((2 * kt + 1) & 3) * 4096, lane, bf, acc);
                stageH(W1p, w, 2 * kt + 4, Wr, lane);
            }
            {   // kt = 30
                long bf = hread(h1L, ln, lq, 14);
                WAIT_VM(8);
                mfma_half<0>(Wr + (size_t)(60 & 3) * 4096, lane, bf, acc);
                stageH(W1p, w, 63, Wr, lane);
                WAIT_VM(8);
                mfma_half<8>(Wr + (size_t)(61 & 3) * 4096, lane, bf, acc);
            }
            {   // kt = 31
                long bf = hread(h1L, ln, lq, 15);
                WAIT_VM(4);
                mfma_half<0>(Wr + (size_t)(62 & 3) * 4096, lane, bf, acc);
                WAIT_VM(0);
                mfma_half<8>(Wr + (size_t)(63 & 3) * 4096, lane, bf, acc);
            }
            int hold[4];
#pragma unroll
            for (int jc = 0; jc < 4; ++jc) {
                int jlb = (w * 4 + jc) * 16 + lq * 4;
                us4 a1v[4];
#pragma unroll
                for (int g = 0; g < 4; ++g) a1v[g] = *(const us4*)(a1Lb + g * 512 + jlb);
                float hv[4];
#pragma unroll
                for (int e = 0; e < 4; ++e) {
                    float pre[4];
#pragma unroll
                    for (int g = 0; g < 4; ++g) pre[g] = acc[jc][g][e] + b2f(a1v[g][e]);
                    float ig = sigf(pre[0]), fg = sigf(pre[1]);
                    float gg = tanhft(pre[2]), og = sigf(pre[3]);
                    float cn = fg * cr1[jc][e] + ig * gg;
                    cr1[jc][e] = cn;
                    hv[e] = og * tanhft(cn);
                }
                int lo = __builtin_amdgcn_cvt_pk_fp8_f32(hv[0], hv[1], 0, false);
                hold[jc] = __builtin_amdgcn_cvt_pk_fp8_f32(hv[2], hv[3], lo, true);
            }
            __syncthreads();                          // all done reading h1L
#pragma unroll
            for (int jc = 0; jc < 4; ++jc) {
                int c = (w * 4 + jc) * 2 + (lq >> 1);
                *(int*)(h1L + ln * 512 + ((c ^ ln) << 3) + (lq & 1) * 4) = hold[jc];
            }
            asm volatile("s_waitcnt lgkmcnt(0)" ::: "memory");
            __syncthreads();                          // h1 new visible
        }
    }

    // ---- final heads on the final h1 (in h1L)
    head2(Wo1p, bo1, Wo2, bo2[0], false, out, Tsz, 44);
    head2(Wg1p, bg1, Wg2, bg2[0], false, out + (size_t)Bsz * Tsz, 1, 0);
}

// ---------------------------------------------------------------------------
extern "C" void kernel_launch(void* const* d_in, const int* in_sizes, int n_in,
                              void* d_out, int out_size, void* d_ws, size_t ws_size,
                              hipStream_t stream)
{
    const float* ef   = (const float*)d_in[0];
    const float* ctx  = (const float*)d_in[1];
    const float* ii   = (const float*)d_in[2];
    const float* Whi  = (const float*)d_in[3];
    const float* bh   = (const float*)d_in[4];
    const float* Wci  = (const float*)d_in[5];
    const float* bc   = (const float*)d_in[6];
    const float* Wih0 = (const float*)d_in[7];
    const float* Whh0 = (const float*)d_in[8];
    const float* bi0  = (const float*)d_in[9];
    const float* bh0  = (const float*)d_in[10];
    const float* Wih1 = (const float*)d_in[11];
    const float* Whh1 = (const float*)d_in[12];
    const float* bi1  = (const float*)d_in[13];
    const float* bh1  = (const float*)d_in[14];
    const float* Wo1  = (const float*)d_in[15];
    const float* bo1  = (const float*)d_in[16];
    const float* Wo2  = (const float*)d_in[17];
    const float* bo2  = (const float*)d_in[18];
    const float* Wg1  = (const float*)d_in[19];
    const float* bg1  = (const float*)d_in[20];
    const float* Wg2  = (const float*)d_in[21];
    const float* bg2  = (const float*)d_in[22];
    float* out = (float*)d_out;

    char* ws = (char*)d_ws;
    size_t off = 0;
    auto take = [&](size_t bytes) -> char* {
        char* pp = ws + off;
        off += (bytes + 255) & ~(size_t)255;
        return pp;
    };
    u8*  W0p     = (u8*)take(2048ull * 512);
    u8*  W1p     = (u8*)take(2048ull * 1024);
    u8*  Wo1p    = (u8*)take(32ull * 512);
    u8*  Wg1p    = (u8*)take(32ull * 512);
    bf16* Wit    = (bf16*)take(4096ull * 256 * 2);
    bf16* efb    = (bf16*)take((size_t)Bsz * Dsz * 2);
    bf16* ctxb   = (bf16*)take((size_t)Bsz * Dsz * 2);
    u8*  h0x     = (u8*)take((size_t)Bsz * Hsz);
    u8*  h1x     = (u8*)take((size_t)Bsz * Hsz);
    float* c0    = (float*)take((size_t)Bsz * Hsz * 4);
    float* c1    = (float*)take((size_t)Bsz * Hsz * 4);
    bf16* ctxg   = (bf16*)take((size_t)Bsz * 2048 * 2);
    (void)ws_size; (void)in_sizes; (void)n_in; (void)out_size;

    k_conv<<<2048, 256, 0, stream>>>(ef, ctx, Whi, Wci, Wih0, Whh0, Wih1, Whh1, Wo1, Wg1,
                                     efb, ctxb, Wit, W0p, W1p, Wo1p, Wg1p);
    k_init<<<dim3(32, 64), 256, 0, stream>>>(efb, ctxb, Wit, bh, bc, bi0, bh0,
                                             h0x, h1x, c0, c1, ctxg);
    k_loop<<<256, 512, 0, stream>>>(h0x, h1x, W0p, W1p, Wo1p, Wg1p,
                                    ctxg, ii, Wih0, bi1, bh1,
                                    bo1, Wo2, bo2, bg1, Wg2, bg2,
                                    c0, c1, out);
}

// Round 16
// 2404.540 us; speedup vs baseline: 6.7309x; 1.0250x over previous
//
#include <hip/hip_runtime.h>
#include <hip/hip_bf16.h>

#define Bsz 4096
#define Dsz 256
#define Hsz 512
#define Tsz 45

typedef __attribute__((ext_vector_type(8))) short short8;
typedef __attribute__((ext_vector_type(4))) float f32x4;
typedef __attribute__((ext_vector_type(4))) unsigned short us4;
typedef __attribute__((ext_vector_type(2))) long lx2;
using bf16 = __hip_bfloat16;
using u8 = unsigned char;

__device__ __forceinline__ float sigf(float x)   { return 1.0f / (1.0f + __expf(-x)); }
__device__ __forceinline__ float tanhft(float x) { return 1.0f - 2.0f / (__expf(2.0f * x) + 1.0f); }
__device__ __forceinline__ float b2f(unsigned short u) { return __uint_as_float((unsigned)u << 16); }
__device__ __forceinline__ u8 f2fp8(float v) {
    int p = __builtin_amdgcn_cvt_pk_fp8_f32(v, v, 0, false);
    return (u8)(p & 0xff);
}

__device__ __forceinline__ void gload16(const void* g, void* l) {
    __builtin_amdgcn_global_load_lds((const __attribute__((address_space(1))) void*)g,
                                     (__attribute__((address_space(3))) void*)l, 16, 0, 0);
}

#define WAIT_VM(N) asm volatile("s_waitcnt vmcnt(" #N ")" ::: "memory")

// ---------------------------------------------------------------------------
// Weight convert/pack (one-shot). PAIR-PACKED fragment blocks: per (kt,wave)
// the 16 frags live as 8 x 1 KB pair-blocks; pair p holds frag 2p in lane
// bytes [0:8) and frag 2p+1 in [8:16) -> one ds_read_b128 yields two frags.
// ---------------------------------------------------------------------------
__global__ void k_conv(const float* __restrict__ ef,   const float* __restrict__ ctx,
                       const float* __restrict__ Whi,  const float* __restrict__ Wci,
                       const float* __restrict__ Wih0, const float* __restrict__ Whh0,
                       const float* __restrict__ Wih1, const float* __restrict__ Whh1,
                       const float* __restrict__ Wo1,  const float* __restrict__ Wg1,
                       bf16* __restrict__ efb,  bf16* __restrict__ ctxb,
                       bf16* __restrict__ Wit,  u8* __restrict__ W0p,
                       u8* __restrict__ W1p,  u8* __restrict__ Wo1p,
                       u8* __restrict__ Wg1p)
{
    size_t tid = (size_t)blockIdx.x * blockDim.x + threadIdx.x;
    size_t gsz = (size_t)gridDim.x * blockDim.x;
    for (size_t i = tid; i < (size_t)Bsz * Dsz; i += gsz) {
        efb[i]  = __float2bfloat16(ef[i]);
        ctxb[i] = __float2bfloat16(ctx[i]);
    }
    for (size_t i = tid; i < 2048ull * 512 / 4; i += gsz) {   // W0p <- Whh0^T
        int n = i >> 7, k = (i & 127) * 4;
        int lo = __builtin_amdgcn_cvt_pk_fp8_f32(Whh0[(size_t)(k+0)*2048+n], Whh0[(size_t)(k+1)*2048+n], 0, false);
        int pk = __builtin_amdgcn_cvt_pk_fp8_f32(Whh0[(size_t)(k+2)*2048+n], Whh0[(size_t)(k+3)*2048+n], lo, true);
        int nb = n >> 4;
        int q = ((nb >> 5) << 2) + (nb & 3);
        size_t dst = (((size_t)(k >> 5) * 8 + ((nb >> 2) & 7)) * 8 + (q >> 1)) * 1024
                   + ((k >> 3) & 3) * 256 + (n & 15) * 16 + (q & 1) * 8 + (k & 4);
        *(int*)(W0p + dst) = pk;
    }
    for (size_t i = tid; i < 2048ull * 1024 / 4; i += gsz) {  // W1p <- [Wih1;Whh1]^T
        int n = i >> 8, k = (i & 255) * 4;
        float f0, f1, f2, f3;
        if (k < 512) {
            f0 = Wih1[(size_t)(k+0)*2048+n]; f1 = Wih1[(size_t)(k+1)*2048+n];
            f2 = Wih1[(size_t)(k+2)*2048+n]; f3 = Wih1[(size_t)(k+3)*2048+n];
        } else {
            int kk = k - 512;
            f0 = Whh1[(size_t)(kk+0)*2048+n]; f1 = Whh1[(size_t)(kk+1)*2048+n];
            f2 = Whh1[(size_t)(kk+2)*2048+n]; f3 = Whh1[(size_t)(kk+3)*2048+n];
        }
        int lo = __builtin_amdgcn_cvt_pk_fp8_f32(f0, f1, 0, false);
        int pk = __builtin_amdgcn_cvt_pk_fp8_f32(f2, f3, lo, true);
        int nb = n >> 4;
        int q = ((nb >> 5) << 2) + (nb & 3);
        size_t dst = (((size_t)(k >> 5) * 8 + ((nb >> 2) & 7)) * 8 + (q >> 1)) * 1024
                   + ((k >> 3) & 3) * 256 + (n & 15) * 16 + (q & 1) * 8 + (k & 4);
        *(int*)(W1p + dst) = pk;
    }
    for (size_t i = tid; i < 32ull * 512 / 4; i += gsz) {     // Wo1p/Wg1p (N=32, nb*16+kt, b64 layout)
        int n = i >> 7, k = (i & 127) * 4;
        size_t dst = ((size_t)(n >> 4) * 16 + (k >> 5)) * 512 + ((k >> 3) & 3) * 128 + (n & 15) * 8 + (k & 4);
        int lo = __builtin_amdgcn_cvt_pk_fp8_f32(Wo1[(size_t)(k+0)*32+n], Wo1[(size_t)(k+1)*32+n], 0, false);
        int pk = __builtin_amdgcn_cvt_pk_fp8_f32(Wo1[(size_t)(k+2)*32+n], Wo1[(size_t)(k+3)*32+n], lo, true);
        *(int*)(Wo1p + dst) = pk;
        lo = __builtin_amdgcn_cvt_pk_fp8_f32(Wg1[(size_t)(k+0)*32+n], Wg1[(size_t)(k+1)*32+n], 0, false);
        pk = __builtin_amdgcn_cvt_pk_fp8_f32(Wg1[(size_t)(k+2)*32+n], Wg1[(size_t)(k+3)*32+n], lo, true);
        *(int*)(Wg1p + dst) = pk;
    }
    for (size_t i = tid; i < 4096ull * 256; i += gsz) {       // Wit[n][k] bf16
        size_t n = i >> 8, k = i & 255;
        float v = (n < 1024) ? Whi[k * 1024 + n]
                : (n < 2048) ? Wci[k * 1024 + (n - 1024)]
                             : Wih0[(1 + k) * 2048 + (n - 2048)];
        Wit[i] = __float2bfloat16(v);
    }
}

// ---------------------------------------------------------------------------
// Init GEMM (bf16): h stored fp8 plain [b][512], c f32, ctxg bf16 [b][j][4g].
// ---------------------------------------------------------------------------
__global__ void __launch_bounds__(256)
k_init(const bf16* __restrict__ efb, const bf16* __restrict__ ctxb,
       const bf16* __restrict__ Wit,
       const float* __restrict__ bh,  const float* __restrict__ bc,
       const float* __restrict__ bi0, const float* __restrict__ bh0,
       u8* __restrict__ h0, u8* __restrict__ h1,
       float* __restrict__ c0, float* __restrict__ c1,
       bf16* __restrict__ ctxg)
{
    const int t = threadIdx.x, lane = t & 63, w = t >> 6;
    const int wr = w >> 1, wc = w & 1;
    const int lq = lane >> 4, ln = lane & 15;
    const int m0 = blockIdx.x * 128, n0 = blockIdx.y * 64;
    const bf16* A = (n0 < 2048) ? efb : ctxb;

    f32x4 zero = {0.f, 0.f, 0.f, 0.f};
    f32x4 acc[4][2];
#pragma unroll
    for (int r = 0; r < 4; ++r)
#pragma unroll
        for (int c = 0; c < 2; ++c) acc[r][c] = zero;

    for (int k0 = 0; k0 < 256; k0 += 32) {
        short8 af[4];
#pragma unroll
        for (int r = 0; r < 4; ++r)
            af[r] = *(const short8*)(A + (size_t)(m0 + wr * 64 + r * 16 + ln) * 256 + k0 + lq * 8);
#pragma unroll
        for (int c = 0; c < 2; ++c) {
            short8 bv = *(const short8*)(Wit + (size_t)(n0 + wc * 32 + c * 16 + ln) * 256 + k0 + lq * 8);
#pragma unroll
            for (int r = 0; r < 4; ++r)
                acc[r][c] = __builtin_amdgcn_mfma_f32_16x16x32_bf16(af[r], bv, acc[r][c], 0, 0, 0);
        }
    }
#pragma unroll
    for (int r = 0; r < 4; ++r)
#pragma unroll
        for (int c = 0; c < 2; ++c)
#pragma unroll
            for (int e = 0; e < 4; ++e) {
                int b = m0 + wr * 64 + r * 16 + lq * 4 + e;
                int n = n0 + wc * 32 + c * 16 + ln;
                float v = acc[r][c][e];
                if (n < 1024) {
                    v += bh[n];
                    if (n < 512) h0[(size_t)b * 512 + n]       = f2fp8(v);
                    else         h1[(size_t)b * 512 + n - 512] = f2fp8(v);
                } else if (n < 2048) {
                    int m = n - 1024; v += bc[m];
                    if (m < 512) c0[(size_t)b * 512 + m]       = v;
                    else         c1[(size_t)b * 512 + m - 512] = v;
                } else {
                    int j = n - 2048;
                    ctxg[(size_t)b * 2048 + (j & 511) * 4 + (j >> 9)] =
                        __float2bfloat16(v + bi0[j] + bh0[j]);
                }
            }
}

// h-LDS B-frag read (B[k][b=ln]): row=ln, chunk c=4kt+lq, swizzle c^ln (4-bit)
__device__ __forceinline__ long hread(const u8* buf, int ln, int lq, int kt) {
    int c = (kt << 2) + lq;
    return *(const long*)(buf + ln * 512 + ((c ^ ln) << 3));
}

// stage one 4 KB half-kt (half h) of the wave's weight stream into ring slot h&3
__device__ __forceinline__ void stageH(const u8* __restrict__ Wp, int w, int h,
                                       u8* Wr, int lane) {
    const u8* src = Wp + ((size_t)((h >> 1) * 8 + w) << 13) + ((size_t)(h & 1) << 12) + lane * 16;
    u8* dst = Wr + ((size_t)(h & 3) << 12);
#pragma unroll
    for (int i = 0; i < 4; ++i)
        gload16(src + i * 1024, dst + i * 1024);
}

// 8 MFMA of one half-kt via 4 x ds_read_b128 (pair-packed frags)
template <int QB>
__device__ __forceinline__ void mfma_half(const u8* slot, int lane, long bf,
                                          f32x4 (&acc)[4][4]) {
#pragma unroll
    for (int i = 0; i < 4; ++i) {
        lx2 v = *(const lx2*)(slot + i * 1024 + lane * 16);
        acc[(QB + 2 * i) & 3][(QB + 2 * i) >> 2] =
            __builtin_amdgcn_mfma_f32_16x16x32_fp8_fp8(v[0], bf, acc[(QB + 2 * i) & 3][(QB + 2 * i) >> 2], 0, 0, 0);
        acc[(QB + 2 * i + 1) & 3][(QB + 2 * i + 1) >> 2] =
            __builtin_amdgcn_mfma_f32_16x16x32_fp8_fp8(v[1], bf, acc[(QB + 2 * i + 1) & 3][(QB + 2 * i + 1) >> 2], 0, 0, 0);
    }
}

// ---------------------------------------------------------------------------
// Persistent T-loop kernel. 256 WGs x 512 thr (16 rows x all 2048 cols/WG).
// Per-wave private ring-4 of 4 KB half-kt slots, counted vmcnt(8), and a
// SEAMLESS ring: each layer's tail stages the next segment's first 3 slots,
// so 12 loads stay in flight across layer/step boundaries (no vmcnt(0)).
// ---------------------------------------------------------------------------
__global__ void __launch_bounds__(512, 1)
k_loop(const u8* __restrict__ h0i, const u8* __restrict__ h1i,
       const u8* __restrict__ W0p, const u8* __restrict__ W1p,
       const u8* __restrict__ Wo1p, const u8* __restrict__ Wg1p,
       const bf16* __restrict__ ctxg, const float* __restrict__ ii,
       const float* __restrict__ w0row,
       const float* __restrict__ bi1, const float* __restrict__ bh1,
       const float* __restrict__ bo1, const float* __restrict__ Wo2,
       const float* __restrict__ bo2,
       const float* __restrict__ bg1, const float* __restrict__ Wg2,
       const float* __restrict__ bg2,
       const float* __restrict__ c0g, const float* __restrict__ c1g,
       float* __restrict__ out)
{
    __shared__ u8 h0L[8192];
    __shared__ u8 h1L[8192];
    __shared__ u8 WringS[8][16384];          // per-wave ring-4 x 4 KB
    __shared__ unsigned short a0Lb[2048];    // w0row as bf16
    __shared__ unsigned short a1Lb[2048];    // bi1+bh1 as bf16
    __shared__ float sit[16];
    __shared__ float spart[16][2];

    const int t = threadIdx.x, lane = t & 63, w = t >> 6;
    const int ln = lane & 15, lq = lane >> 4;
    const int m0 = blockIdx.x * 16;
    const int b = m0 + ln;
    u8* Wr = WringS[w];
    f32x4 zero = {0.f, 0.f, 0.f, 0.f};

    // ---- prologue: h-init -> LDS (swizzled chunk^row); biases -> LDS bf16
#pragma unroll
    for (int i = 0; i < 2; ++i) {
        int cid = i * 512 + t;
        int row = cid >> 6, c = cid & 63;
        long v0 = *(const long*)(h0i + (size_t)(m0 + row) * 512 + c * 8);
        long v1 = *(const long*)(h1i + (size_t)(m0 + row) * 512 + c * 8);
        int pc = row * 512 + ((c ^ row) << 3);
        *(long*)(&h0L[pc]) = v0;
        *(long*)(&h1L[pc]) = v1;
    }
#pragma unroll
    for (int i = 0; i < 4; ++i) {
        int idx = i * 512 + t;
        a0Lb[idx] = (unsigned short)(__bfloat16_as_ushort(__float2bfloat16(w0row[idx])));
        a1Lb[idx] = (unsigned short)(__bfloat16_as_ushort(__float2bfloat16(bi1[idx] + bh1[idx])));
    }
    // ---- per-thread resident state: c and ctxg at (b=ln, jl=(w*4+jc)*16+lq*4+e)
    f32x4 cr0[4], cr1[4];
    us4 xg[4][4];
#pragma unroll
    for (int jc = 0; jc < 4; ++jc) {
        int jlb = (w * 4 + jc) * 16 + lq * 4;
        cr0[jc] = *(const f32x4*)(c0g + (size_t)b * 512 + jlb);
        cr1[jc] = *(const f32x4*)(c1g + (size_t)b * 512 + jlb);
#pragma unroll
        for (int e = 0; e < 4; ++e)
            xg[jc][e] = *(const us4*)((const unsigned short*)ctxg + (size_t)b * 2048 + (jlb + e) * 4);
    }
    __syncthreads();

    // intent head: waves 0,1 do j-tiles 0,1; all threads call (barriers inside)
    auto head2 = [&](const u8* Wp, const float* b1, const float* W2, float b2s,
                     bool tosit, float* dst, int stride, int scol) {
        if (w < 2) {
            f32x4 acc = zero;
#pragma unroll
            for (int kt = 0; kt < 16; ++kt) {
                long bf = hread(h1L, ln, lq, kt);
                long af = *(const long*)(Wp + (size_t)(w * 16 + kt) * 512 + lane * 8);
                acc = __builtin_amdgcn_mfma_f32_16x16x32_fp8_fp8(af, bf, acc, 0, 0, 0);
            }
            float v = 0.f;
#pragma unroll
            for (int e = 0; e < 4; ++e) {
                int j = w * 16 + lq * 4 + e;
                v += fmaxf(acc[e] + b1[j], 0.f) * W2[j];
            }
            v += __shfl_xor(v, 16);
            v += __shfl_xor(v, 32);
            if (lq == 0) spart[ln][w] = v;
        }
        __syncthreads();
        if (t < 16) {
            float pv = sigf(spart[t][0] + spart[t][1] + b2s);
            if (tosit) sit[t] = pv;
            if (dst) dst[(size_t)(m0 + t) * stride + scol] = pv;
        }
        __syncthreads();
    };

    // seed the ring for step 0's layer 0
    stageH(W0p, w, 0, Wr, lane);
    stageH(W0p, w, 1, Wr, lane);
    stageH(W0p, w, 2, Wr, lane);

    for (int s = 0; s < Tsz; ++s) {
        if (s == 0) {
            if (t < 16) sit[t] = ii[m0 + t];
            __syncthreads();
        } else {
            head2(Wo1p, bo1, Wo2, bo2[0], true, out, Tsz, s - 1);
        }
        const float sval = sit[ln];

        // ================= layer 0: G = W0·h0^T, K=512 (H=32 halves) =======
        {
            f32x4 acc[4][4];
#pragma unroll
            for (int jc = 0; jc < 4; ++jc)
#pragma unroll
                for (int g = 0; g < 4; ++g) acc[jc][g] = zero;

#pragma unroll 2
            for (int kt = 0; kt < 14; ++kt) {
                long bf = hread(h0L, ln, lq, kt);
                WAIT_VM(8);
                mfma_half<0>(Wr + (size_t)((2 * kt) & 3) * 4096, lane, bf, acc);
                stageH(W0p, w, 2 * kt + 3, Wr, lane);
                WAIT_VM(8);
                mfma_half<8>(Wr + (size_t)((2 * kt + 1) & 3) * 4096, lane, bf, acc);
                stageH(W0p, w, 2 * kt + 4, Wr, lane);
            }
            {   // kt = 14: last W0 stage + begin staging layer-1's ring
                long bf = hread(h0L, ln, lq, 14);
                WAIT_VM(8);
                mfma_half<0>(Wr + (size_t)(28 & 3) * 4096, lane, bf, acc);
                stageH(W0p, w, 31, Wr, lane);
                WAIT_VM(8);
                mfma_half<8>(Wr + (size_t)(29 & 3) * 4096, lane, bf, acc);
                stageH(W1p, w, 0, Wr, lane);          // L1 h0 -> slot 0
            }
            {   // kt = 15
                long bf = hread(h0L, ln, lq, 15);
                WAIT_VM(8);
                mfma_half<0>(Wr + (size_t)(30 & 3) * 4096, lane, bf, acc);
                stageH(W1p, w, 1, Wr, lane);          // L1 h1 -> slot 1
                WAIT_VM(8);
                mfma_half<8>(Wr + (size_t)(31 & 3) * 4096, lane, bf, acc);
                stageH(W1p, w, 2, Wr, lane);          // L1 h2 -> slot 2
            }
            // epilogue: cell from resident state only; L1 stages fly meanwhile
            int hold[4];
#pragma unroll
            for (int jc = 0; jc < 4; ++jc) {
                int jlb = (w * 4 + jc) * 16 + lq * 4;
                us4 a0v[4];
#pragma unroll
                for (int g = 0; g < 4; ++g) a0v[g] = *(const us4*)(a0Lb + g * 512 + jlb);
                float hv[4];
#pragma unroll
                for (int e = 0; e < 4; ++e) {
                    float pre[4];
#pragma unroll
                    for (int g = 0; g < 4; ++g)
                        pre[g] = acc[jc][g][e] + b2f(xg[jc][e][g]) + sval * b2f(a0v[g][e]);
                    float ig = sigf(pre[0]), fg = sigf(pre[1]);
                    float gg = tanhft(pre[2]), og = sigf(pre[3]);
                    float cn = fg * cr0[jc][e] + ig * gg;
                    cr0[jc][e] = cn;
                    hv[e] = og * tanhft(cn);
                }
                int lo = __builtin_amdgcn_cvt_pk_fp8_f32(hv[0], hv[1], 0, false);
                hold[jc] = __builtin_amdgcn_cvt_pk_fp8_f32(hv[2], hv[3], lo, true);
            }
            __syncthreads();                          // all done reading h0L
#pragma unroll
            for (int jc = 0; jc < 4; ++jc) {
                int c = (w * 4 + jc) * 2 + (lq >> 1);
                *(int*)(h0L + ln * 512 + ((c ^ ln) << 3) + (lq & 1) * 4) = hold[jc];
            }
            asm volatile("s_waitcnt lgkmcnt(0)" ::: "memory");
            __syncthreads();                          // h0 new visible
        }

        // ====== layer 1: G = W1·[h0;h1]^T, K=1024 (H=64 halves) ===========
        {
            f32x4 acc[4][4];
#pragma unroll
            for (int jc = 0; jc < 4; ++jc)
#pragma unroll
                for (int g = 0; g < 4; ++g) acc[jc][g] = zero;

#pragma unroll 2
            for (int kt = 0; kt < 16; ++kt) {
                long bf = hread(h0L, ln, lq, kt);
                WAIT_VM(8);
                mfma_half<0>(Wr + (size_t)((2 * kt) & 3) * 4096, lane, bf, acc);
                stageH(W1p, w, 2 * kt + 3, Wr, lane);
                WAIT_VM(8);
                mfma_half<8>(Wr + (size_t)((2 * kt + 1) & 3) * 4096, lane, bf, acc);
                stageH(W1p, w, 2 * kt + 4, Wr, lane);
            }
#pragma unroll 2
            for (int kt = 16; kt < 30; ++kt) {
                long bf = hread(h1L, ln, lq, kt - 16);
                WAIT_VM(8);
                mfma_half<0>(Wr + (size_t)((2 * kt) & 3) * 4096, lane, bf, acc);
                stageH(W1p, w, 2 * kt + 3, Wr, lane);
                WAIT_VM(8);
                mfma_half<8>(Wr + (size_t)((2 * kt + 1) & 3) * 4096, lane, bf, acc);
                stageH(W1p, w, 2 * kt + 4, Wr, lane);
            }
            {   // kt = 30: last W1 stage + begin staging next step's layer-0
                long bf = hread(h1L, ln, lq, 14);
                WAIT_VM(8);
                mfma_half<0>(Wr + (size_t)(60 & 3) * 4096, lane, bf, acc);
                stageH(W1p, w, 63, Wr, lane);
                WAIT_VM(8);
                mfma_half<8>(Wr + (size_t)(61 & 3) * 4096, lane, bf, acc);
                stageH(W0p, w, 0, Wr, lane);          // next L0 h0 -> slot 0
            }
            {   // kt = 31
                long bf = hread(h1L, ln, lq, 15);
                WAIT_VM(8);
                mfma_half<0>(Wr + (size_t)(62 & 3) * 4096, lane, bf, acc);
                stageH(W0p, w, 1, Wr, lane);          // next L0 h1 -> slot 1
                WAIT_VM(8);
                mfma_half<8>(Wr + (size_t)(63 & 3) * 4096, lane, bf, acc);
                stageH(W0p, w, 2, Wr, lane);          // next L0 h2 -> slot 2
            }
            int hold[4];
#pragma unroll
            for (int jc = 0; jc < 4; ++jc) {
                int jlb = (w * 4 + jc) * 16 + lq * 4;
                us4 a1v[4];
#pragma unroll
                for (int g = 0; g < 4; ++g) a1v[g] = *(const us4*)(a1Lb + g * 512 + jlb);
                float hv[4];
#pragma unroll
                for (int e = 0; e < 4; ++e) {
                    float pre[4];
#pragma unroll
                    for (int g = 0; g < 4; ++g) pre[g] = acc[jc][g][e] + b2f(a1v[g][e]);
                    float ig = sigf(pre[0]), fg = sigf(pre[1]);
                    float gg = tanhft(pre[2]), og = sigf(pre[3]);
                    float cn = fg * cr1[jc][e] + ig * gg;
                    cr1[jc][e] = cn;
                    hv[e] = og * tanhft(cn);
                }
                int lo = __builtin_amdgcn_cvt_pk_fp8_f32(hv[0], hv[1], 0, false);
                hold[jc] = __builtin_amdgcn_cvt_pk_fp8_f32(hv[2], hv[3], lo, true);
            }
            __syncthreads();                          // all done reading h1L
#pragma unroll
            for (int jc = 0; jc < 4; ++jc) {
                int c = (w * 4 + jc) * 2 + (lq >> 1);
                *(int*)(h1L + ln * 512 + ((c ^ ln) << 3) + (lq & 1) * 4) = hold[jc];
            }
            asm volatile("s_waitcnt lgkmcnt(0)" ::: "memory");
            __syncthreads();                          // h1 new visible
        }
    }

    // ---- final heads on the final h1 (in h1L); stray staged loads are benign
    head2(Wo1p, bo1, Wo2, bo2[0], false, out, Tsz, 44);
    head2(Wg1p, bg1, Wg2, bg2[0], false, out + (size_t)Bsz * Tsz, 1, 0);
}

// ---------------------------------------------------------------------------
extern "C" void kernel_launch(void* const* d_in, const int* in_sizes, int n_in,
                              void* d_out, int out_size, void* d_ws, size_t ws_size,
                              hipStream_t stream)
{
    const float* ef   = (const float*)d_in[0];
    const float* ctx  = (const float*)d_in[1];
    const float* ii   = (const float*)d_in[2];
    const float* Whi  = (const float*)d_in[3];
    const float* bh   = (const float*)d_in[4];
    const float* Wci  = (const float*)d_in[5];
    const float* bc   = (const float*)d_in[6];
    const float* Wih0 = (const float*)d_in[7];
    const float* Whh0 = (const float*)d_in[8];
    const float* bi0  = (const float*)d_in[9];
    const float* bh0  = (const float*)d_in[10];
    const float* Wih1 = (const float*)d_in[11];
    const float* Whh1 = (const float*)d_in[12];
    const float* bi1  = (const float*)d_in[13];
    const float* bh1  = (const float*)d_in[14];
    const float* Wo1  = (const float*)d_in[15];
    const float* bo1  = (const float*)d_in[16];
    const float* Wo2  = (const float*)d_in[17];
    const float* bo2  = (const float*)d_in[18];
    const float* Wg1  = (const float*)d_in[19];
    const float* bg1  = (const float*)d_in[20];
    const float* Wg2  = (const float*)d_in[21];
    const float* bg2  = (const float*)d_in[22];
    float* out = (float*)d_out;

    char* ws = (char*)d_ws;
    size_t off = 0;
    auto take = [&](size_t bytes) -> char* {
        char* pp = ws + off;
        off += (bytes + 255) & ~(size_t)255;
        return pp;
    };
    u8*  W0p     = (u8*)take(2048ull * 512);
    u8*  W1p     = (u8*)take(2048ull * 1024);
    u8*  Wo1p    = (u8*)take(32ull * 512);
    u8*  Wg1p    = (u8*)take(32ull * 512);
    bf16* Wit    = (bf16*)take(4096ull * 256 * 2);
    bf16* efb    = (bf16*)take((size_t)Bsz * Dsz * 2);
    bf16* ctxb   = (bf16*)take((size_t)Bsz * Dsz * 2);
    u8*  h0x     = (u8*)take((size_t)Bsz * Hsz);
    u8*  h1x     = (u8*)take((size_t)Bsz * Hsz);
    float* c0    = (float*)take((size_t)Bsz * Hsz * 4);
    float* c1    = (float*)take((size_t)Bsz * Hsz * 4);
    bf16* ctxg   = (bf16*)take((size_t)Bsz * 2048 * 2);
    (void)ws_size; (void)in_sizes; (void)n_in; (void)out_size;

    k_conv<<<2048, 256, 0, stream>>>(ef, ctx, Whi, Wci, Wih0, Whh0, Wih1, Whh1, Wo1, Wg1,
                                     efb, ctxb, Wit, W0p, W1p, Wo1p, Wg1p);
    k_init<<<dim3(32, 64), 256, 0, stream>>>(efb, ctxb, Wit, bh, bc, bi0, bh0,
                                             h0x, h1x, c0, c1, ctxg);
    k_loop<<<256, 512, 0, stream>>>(h0x, h1x, W0p, W1p, Wo1p, Wg1p,
                                    ctxg, ii, Wih0, bi1, bh1,
                                    bo1, Wo2, bo2, bg1, Wg2, bg2,
                                    c0, c1, out);
}